// Round 8
// baseline (163.089 us; speedup 1.0000x reference)
//
#include <hip/hip_runtime.h>
#include <cmath>

#define B_ 2
#define N_ 2048
#define D_ 1024
#define H_ 16

typedef __attribute__((ext_vector_type(8))) short short8;
typedef __attribute__((ext_vector_type(4))) float f32x4;
typedef __attribute__((ext_vector_type(4))) unsigned short u16x4;

__device__ __forceinline__ unsigned short f2bf(float f) {
    union { float f; unsigned u; } x;
    x.f = f;
    unsigned r = x.u + 0x7FFFu + ((x.u >> 16) & 1u);
    return (unsigned short)(r >> 16);
}
__device__ __forceinline__ unsigned cvt_pk_bf16(float lo, float hi) {
    unsigned r;
    asm("v_cvt_pk_bf16_f32 %0, %1, %2" : "=v"(r) : "v"(lo), "v"(hi));
    return r;
}
__device__ __forceinline__ float exp2_fast(float x) {
    float r;
    asm("v_exp_f32 %0, %1" : "=v"(r) : "v"(x));
    return r;
}
__device__ __forceinline__ void gload_lds16(const void* g, void* l) {
    __builtin_amdgcn_global_load_lds((const __attribute__((address_space(1))) unsigned*)g,
                                     (__attribute__((address_space(3))) unsigned*)l,
                                     16, 0, 0);
}

// ---------------- cos/sin tables (trig once; q table pre-scaled by 0.125*log2e) ----------------
__global__ __launch_bounds__(256) void freqtab_kernel(const float* __restrict__ pos,
                                                      float2* __restrict__ tabq,
                                                      float2* __restrict__ tabk) {
    const int idx = blockIdx.x * 256 + threadIdx.x;   // N_*64 = 131072
    const float f = pos[idx];
    const float cc = cosf(f), ss = sinf(f);
    const float sq = 0.125f * 1.4426950408889634f;    // DH^-0.5 * log2(e)
    tabq[idx] = make_float2(sq * cc, sq * ss);
    tabk[idx] = make_float2(cc, ss);
}

// ---------------- RMS-like norm -> bf16 xn, plus bf16 copy of x ----------------
__global__ __launch_bounds__(256) void rmsnorm_kernel(const float* __restrict__ x,
                                                      const float* __restrict__ gamma,
                                                      unsigned short* __restrict__ xn,
                                                      unsigned short* __restrict__ xb) {
    const int row = blockIdx.x;
    const float4 v = reinterpret_cast<const float4*>(x + (size_t)row * D_)[threadIdx.x];
    float ss = v.x * v.x + v.y * v.y + v.z * v.z + v.w * v.w;
    #pragma unroll
    for (int off = 32; off; off >>= 1) ss += __shfl_xor(ss, off, 64);
    __shared__ float wss[4];
    if ((threadIdx.x & 63) == 0) wss[threadIdx.x >> 6] = ss;
    __syncthreads();
    const float tot = wss[0] + wss[1] + wss[2] + wss[3];
    const float inv = 1.0f / fmaxf(sqrtf(tot * (1.0f / D_)), 1e-8f);
    const float4 g = reinterpret_cast<const float4*>(gamma)[threadIdx.x];
    u16x4 on, ox;
    on[0] = f2bf(v.x * inv * g.x); on[1] = f2bf(v.y * inv * g.y);
    on[2] = f2bf(v.z * inv * g.z); on[3] = f2bf(v.w * inv * g.w);
    ox[0] = f2bf(v.x); ox[1] = f2bf(v.y); ox[2] = f2bf(v.z); ox[3] = f2bf(v.w);
    *reinterpret_cast<u16x4*>(xn + (size_t)row * D_ + threadIdx.x * 4) = on;
    *reinterpret_cast<u16x4*>(xb + (size_t)row * D_ + threadIdx.x * 4) = ox;
}

// ---------------- all 3 weight transposes in one kernel ----------------
__global__ __launch_bounds__(256) void convT_all_kernel(const float* __restrict__ Wq,
                                                        const float* __restrict__ Wkv,
                                                        const float* __restrict__ Wo,
                                                        unsigned short* __restrict__ Wqt,
                                                        unsigned short* __restrict__ Wkvt,
                                                        unsigned short* __restrict__ Wot) {
    __shared__ float tile[32][33];
    const int bx = blockIdx.x;   // 0..127 over concat {Wq:32, Wkv:64, Wo:32}
    const float* W;
    unsigned short* Wt;
    int Nm, n0;
    if (bx < 32)       { W = Wq;  Wt = Wqt;  Nm = 1024; n0 = bx * 32; }
    else if (bx < 96)  { W = Wkv; Wt = Wkvt; Nm = 2048; n0 = (bx - 32) * 32; }
    else               { W = Wo;  Wt = Wot;  Nm = 1024; n0 = (bx - 96) * 32; }
    const int k0 = blockIdx.y * 32;
    const int r = threadIdx.x >> 3, c4 = (threadIdx.x & 7) * 4;
    const float4 ld = *reinterpret_cast<const float4*>(W + (size_t)(k0 + r) * Nm + n0 + c4);
    tile[r][c4 + 0] = ld.x; tile[r][c4 + 1] = ld.y;
    tile[r][c4 + 2] = ld.z; tile[r][c4 + 3] = ld.w;
    __syncthreads();
    u16x4 o;
    #pragma unroll
    for (int j = 0; j < 4; ++j) o[j] = f2bf(tile[c4 + j][r]);
    *reinterpret_cast<u16x4*>(Wt + (size_t)(n0 + r) * 1024 + k0 + c4) = o;
}

// ---------------- V half (vb) -> Vt[bh][d][n] (bf16) ----------------
__global__ __launch_bounds__(256) void transposeV_kernel(const unsigned short* __restrict__ vb,
                                                         unsigned short* __restrict__ vt) {
    __shared__ unsigned short tile[64][72];
    const int bh = blockIdx.y;
    const int b = bh >> 4, h = bh & 15;
    const int n0 = blockIdx.x * 64;
    const int tid = threadIdx.x;
    const int r = tid >> 3, c = (tid & 7) * 8;
    #pragma unroll
    for (int i = 0; i < 2; ++i) {
        const int n = i * 32 + r;
        const short8 v = *reinterpret_cast<const short8*>(
            vb + (size_t)(b * N_ + n0 + n) * 1024 + h * 64 + c);
        *reinterpret_cast<short8*>(&tile[n][c]) = v;
    }
    __syncthreads();
    #pragma unroll
    for (int i = 0; i < 2; ++i) {
        const int d = i * 32 + r;
        short8 o;
        #pragma unroll
        for (int j = 0; j < 8; ++j) o[j] = (short)tile[c + j][d];
        *reinterpret_cast<short8*>(vt + ((size_t)bh * 64 + d) * 2048 + n0 + c) = o;
    }
}

// ---------------- bf16 MFMA GEMM ----------------
// MODE 0: f32 out + bias. MODE 2: rope epilogue -> bf16 Cout (q). MODE 3: kv split —
// blocks x<8 write roped K to Cout (kb), x>=8 write plain V to Cout2 (vb). All dst stride 1024.
template <int BN, int MODE>
__global__ __launch_bounds__(256) void gemm_bf16(const unsigned short* __restrict__ A,
                                                 const unsigned short* __restrict__ Bt,
                                                 const float* __restrict__ bias,
                                                 void* __restrict__ Cout,
                                                 void* __restrict__ Cout2,
                                                 const float2* __restrict__ tab,
                                                 int K) {
    constexpr int WN = BN / 2;
    constexpr int NF = BN / 32;
    __shared__ unsigned short As[128 * 64];
    __shared__ unsigned short Bs[BN * 64];
    const int tid = threadIdx.x, lane = tid & 63, w = tid >> 6;
    const int m0 = blockIdx.y * 128, n0 = blockIdx.x * BN;
    const int wm = w >> 1, wn = w & 1;
    const int cc = lane & 15;

    const int sr = tid >> 3;
    const int sc = (tid & 7) * 8;

    f32x4 acc[4][NF] = {};

    for (int k0 = 0; k0 < K; k0 += 64) {
        __syncthreads();
        #pragma unroll
        for (int i = 0; i < 4; ++i) {
            const int r = i * 32 + sr;
            const unsigned short* src = A + (size_t)(m0 + r) * K + k0 + (sc ^ ((r & 7) << 3));
            gload_lds16(src, (char*)As + i * 4096 + w * 1024);
        }
        #pragma unroll
        for (int i = 0; i < NF; ++i) {
            const int r = i * 32 + sr;
            const unsigned short* src = Bt + (size_t)(n0 + r) * K + k0 + (sc ^ ((r & 7) << 3));
            gload_lds16(src, (char*)Bs + i * 4096 + w * 1024);
        }
        __syncthreads();

        short8 af[4][2], bf[NF][2];
        #pragma unroll
        for (int mf = 0; mf < 4; ++mf)
            #pragma unroll
            for (int ks = 0; ks < 2; ++ks) {
                const int r = wm * 64 + mf * 16 + cc;
                const int cb = (ks * 64 + ((lane >> 4) * 16)) ^ ((r & 7) << 4);
                af[mf][ks] = *reinterpret_cast<const short8*>((const char*)As + r * 128 + cb);
            }
        #pragma unroll
        for (int nf = 0; nf < NF; ++nf)
            #pragma unroll
            for (int ks = 0; ks < 2; ++ks) {
                const int r = wn * WN + nf * 16 + cc;
                const int cb = (ks * 64 + ((lane >> 4) * 16)) ^ ((r & 7) << 4);
                bf[nf][ks] = *reinterpret_cast<const short8*>((const char*)Bs + r * 128 + cb);
            }
        #pragma unroll
        for (int ks = 0; ks < 2; ++ks)
            #pragma unroll
            for (int mf = 0; mf < 4; ++mf)
                #pragma unroll
                for (int nf = 0; nf < NF; ++nf)
                    acc[mf][nf] = __builtin_amdgcn_mfma_f32_16x16x32_bf16(af[mf][ks], bf[nf][ks], acc[mf][nf], 0, 0, 0);
    }

    if (MODE == 0) {
        float bb[NF];
        #pragma unroll
        for (int nf = 0; nf < NF; ++nf)
            bb[nf] = bias[n0 + wn * WN + nf * 16 + cc];
        #pragma unroll
        for (int mf = 0; mf < 4; ++mf)
            #pragma unroll
            for (int nf = 0; nf < NF; ++nf)
                #pragma unroll
                for (int reg = 0; reg < 4; ++reg) {
                    const int row = m0 + wm * 64 + mf * 16 + (lane >> 4) * 4 + reg;
                    const int col = n0 + wn * WN + nf * 16 + cc;
                    ((float*)Cout)[(size_t)row * 1024 + col] = acc[mf][nf][reg] + bb[nf];
                }
    } else if (MODE == 3 && blockIdx.x >= 8) {
        // V half: plain bf16 -> Cout2 (vb), col - 1024
        #pragma unroll
        for (int mf = 0; mf < 4; ++mf)
            #pragma unroll
            for (int nf = 0; nf < NF; ++nf)
                #pragma unroll
                for (int reg = 0; reg < 4; ++reg) {
                    const int row = m0 + wm * 64 + mf * 16 + (lane >> 4) * 4 + reg;
                    const int col = n0 + wn * WN + nf * 16 + cc - 1024;
                    ((unsigned short*)Cout2)[(size_t)row * 1024 + col] = f2bf(acc[mf][nf][reg]);
                }
    } else {
        // rope epilogue (q, or K half of kv): pairs (d, d+32) = (nf, nf+2), head-local d = nf*16+cc
        #pragma unroll
        for (int mf = 0; mf < 4; ++mf)
            #pragma unroll
            for (int reg = 0; reg < 4; ++reg) {
                const int row = m0 + wm * 64 + mf * 16 + (lane >> 4) * 4 + reg;
                const int n = row & (N_ - 1);
                #pragma unroll
                for (int nf = 0; nf < 2; ++nf) {
                    const int d = nf * 16 + cc;
                    const float2 t1 = tab[n * 64 + d];
                    const float2 t2 = tab[n * 64 + 32 + d];
                    const float x1 = acc[mf][nf][reg];
                    const float x2 = acc[mf][nf + 2][reg];
                    const float o1 = x1 * t1.x - x2 * t1.y;
                    const float o2 = x2 * t2.x + x1 * t2.y;
                    const int col = n0 + wn * WN + nf * 16 + cc;
                    ((unsigned short*)Cout)[(size_t)row * 1024 + col] = f2bf(o1);
                    ((unsigned short*)Cout)[(size_t)row * 1024 + col + 32] = f2bf(o2);
                }
            }
    }
}

// ---------------- bf16 MFMA causal flash attention, paired q-tiles (uniform work) ----------------
// grid (N/128, B*H): block j handles q-tiles j (lo) and nq-1-j (hi); per block work
// = (nq-j) + (j+1) = nq+1 tile-units, uniform. K fragments shared between lo and hi.
// exp2-domain softmax (q pre-scaled by 0.125*log2e), defer-max (THR=8),
// K double-buffered, V single-buffered (issued post-barrier, hides under next QK^T).
__global__ __launch_bounds__(256, 4) void attn_mfma_kernel(const unsigned short* __restrict__ q,
                                                           const unsigned short* __restrict__ kb,
                                                           const unsigned short* __restrict__ vt,
                                                           unsigned short* __restrict__ att) {
    const int bh = blockIdx.y;
    const int b = bh >> 4, h = bh & 15;
    const int j = blockIdx.x;          // lo q-tile index
    const int nq = N_ / 64;            // 32
    const int lo_qb = j * 64;
    const int hi_qb = (nq - 1 - j) * 64;
    const int nt = nq - j;             // iterations (hi tile count)
    const int lo_nt = j + 1;           // lo active for t < lo_nt
    const int tid = threadIdx.x;
    const int lane = tid & 63;
    const int w = tid >> 6;
    const int c = lane & 15;
    const int g = lane >> 4;

    __shared__ __align__(16) unsigned short Ks[2][64 * 64];   // [key][d] swizzled (dbuf)
    __shared__ __align__(16) unsigned short Vs[64 * 64];      // [d][key] swizzled (single)
    __shared__ __align__(16) unsigned short Ps[4][1024];      // per-wave P^T staging
    char* const PB = (char*)&Ps[w][0];

    const int qrow_lo = lo_qb + w * 16 + c;
    const int qrow_hi = hi_qb + w * 16 + c;
    short8 qfl[2], qfh[2];
    {
        const unsigned short* qp = q + (size_t)(b * N_ + qrow_lo) * 1024 + h * 64 + g * 8;
        qfl[0] = *reinterpret_cast<const short8*>(qp);
        qfl[1] = *reinterpret_cast<const short8*>(qp + 32);
        qp = q + (size_t)(b * N_ + qrow_hi) * 1024 + h * 64 + g * 8;
        qfh[0] = *reinterpret_cast<const short8*>(qp);
        qfh[1] = *reinterpret_cast<const short8*>(qp + 32);
    }

    float m_lo = -1e30f, l_lo = 0.f, m_hi = -1e30f, l_hi = 0.f;
    f32x4 oacc_lo[4] = {}, oacc_hi[4] = {};

    const int sr = tid >> 3, sc = (tid & 7) * 8;
    const unsigned short* kbase = kb + (size_t)b * N_ * 1024 + h * 64;
    const unsigned short* vbase = vt + (size_t)bh * 64 * 2048;

    // prologue: stage K0 + V0
    #pragma unroll
    for (int i = 0; i < 2; ++i) {
        const int r = i * 32 + sr;
        const int cs = sc ^ ((r & 7) << 3);
        gload_lds16(kbase + (size_t)r * 1024 + cs, (char*)Ks[0] + i * 4096 + w * 1024);
        gload_lds16(vbase + (size_t)r * 2048 + cs, (char*)Vs + i * 4096 + w * 1024);
    }

    for (int t = 0; t < nt; ++t) {
        const int jb = t * 64;
        const int jn = jb + 64;
        if (t + 1 < nt) {
            char* kd = (char*)Ks[(t + 1) & 1];
            #pragma unroll
            for (int i = 0; i < 2; ++i) {
                const int r = i * 32 + sr;
                const int cs = sc ^ ((r & 7) << 3);
                gload_lds16(kbase + (size_t)(jn + r) * 1024 + cs, kd + i * 4096 + w * 1024);
            }
            asm volatile("s_waitcnt vmcnt(2)" ::: "memory");  // own K[t],V[t] landed; K[t+1] flying
        } else {
            asm volatile("s_waitcnt vmcnt(0)" ::: "memory");
        }
        __builtin_amdgcn_s_barrier();

        const char* Ksc = (const char*)Ks[t & 1];
        const char* Vsc = (const char*)Vs;

        // K fragments, shared by lo and hi
        short8 kf[4][2];
        #pragma unroll
        for (int ct = 0; ct < 4; ++ct)
            #pragma unroll
            for (int ks = 0; ks < 2; ++ks) {
                const int key = ct * 16 + c;
                const int addr = (key * 128 + ks * 64 + g * 16) ^ ((key & 7) << 4);
                kf[ct][ks] = *reinterpret_cast<const short8*>(Ksc + addr);
            }

        auto process = [&](const short8 (&qf)[2], float& m, float& l, f32x4 (&oacc)[4],
                           const int qrow, const bool need_mask) {
            // S^T = K·Q^T : lane holds row=qrow, key = jb + ct*16 + g*4 + reg
            f32x4 st[4];
            __builtin_amdgcn_s_setprio(1);
            #pragma unroll
            for (int ct = 0; ct < 4; ++ct) {
                f32x4 acc = {0.f, 0.f, 0.f, 0.f};
                acc = __builtin_amdgcn_mfma_f32_16x16x32_bf16(kf[ct][0], qf[0], acc, 0, 0, 0);
                acc = __builtin_amdgcn_mfma_f32_16x16x32_bf16(kf[ct][1], qf[1], acc, 0, 0, 0);
                st[ct] = acc;
            }
            __builtin_amdgcn_s_setprio(0);

            float mx = -1e30f;
            if (need_mask) {
                #pragma unroll
                for (int ct = 0; ct < 4; ++ct)
                    #pragma unroll
                    for (int reg = 0; reg < 4; ++reg) {
                        const int key = jb + ct * 16 + g * 4 + reg;
                        const float sv = (key <= qrow) ? st[ct][reg] : -1e30f;
                        st[ct][reg] = sv;
                        mx = fmaxf(mx, sv);
                    }
            } else {
                #pragma unroll
                for (int ct = 0; ct < 4; ++ct)
                    mx = fmaxf(mx, fmaxf(fmaxf(st[ct][0], st[ct][1]),
                                         fmaxf(st[ct][2], st[ct][3])));
            }
            mx = fmaxf(mx, __shfl_xor(mx, 16, 64));
            mx = fmaxf(mx, __shfl_xor(mx, 32, 64));
            if (!__all(mx <= m + 8.0f)) {
                const float mn = fmaxf(m, mx);
                const float corr = exp2_fast(m - mn);
                l *= corr;
                m = mn;
                #pragma unroll
                for (int dt = 0; dt < 4; ++dt) {
                    oacc[dt][0] *= corr; oacc[dt][1] *= corr;
                    oacc[dt][2] *= corr; oacc[dt][3] *= corr;
                }
            }
            float rs = 0.f;
            #pragma unroll
            for (int ct = 0; ct < 4; ++ct)
                #pragma unroll
                for (int reg = 0; reg < 4; ++reg) {
                    const float p = exp2_fast(st[ct][reg] - m);
                    st[ct][reg] = p;
                    rs += p;
                }
            rs += __shfl_xor(rs, 16, 64);
            rs += __shfl_xor(rs, 32, 64);
            l += rs;

            // P^T -> per-wave LDS
            #pragma unroll
            for (int ct = 0; ct < 4; ++ct) {
                uint2 u;
                u.x = cvt_pk_bf16(st[ct][0], st[ct][1]);
                u.y = cvt_pk_bf16(st[ct][2], st[ct][3]);
                const int addr = (c * 128 + ct * 32 + g * 8) ^ ((c & 7) << 4);
                *reinterpret_cast<uint2*>(PB + addr) = u;
            }
            short8 pf[2];
            #pragma unroll
            for (int ks = 0; ks < 2; ++ks) {
                const int addr = (c * 128 + ks * 64 + g * 16) ^ ((c & 7) << 4);
                pf[ks] = *reinterpret_cast<const short8*>(PB + addr);
            }
            // O^T += V^T · P^T
            __builtin_amdgcn_s_setprio(1);
            #pragma unroll
            for (int dt = 0; dt < 4; ++dt) {
                #pragma unroll
                for (int ks = 0; ks < 2; ++ks) {
                    const int vd = dt * 16 + c;
                    const int addr = (vd * 128 + ks * 64 + g * 16) ^ ((vd & 7) << 4);
                    const short8 vf = *reinterpret_cast<const short8*>(Vsc + addr);
                    oacc[dt] = __builtin_amdgcn_mfma_f32_16x16x32_bf16(vf, pf[ks], oacc[dt], 0, 0, 0);
                }
            }
            __builtin_amdgcn_s_setprio(0);
        };

        process(qfh, m_hi, l_hi, oacc_hi, qrow_hi, t == nt - 1);
        if (t < lo_nt)
            process(qfl, m_lo, l_lo, oacc_lo, qrow_lo, t == lo_nt - 1);

        __builtin_amdgcn_s_barrier();   // all waves done reading Vs / this K buf

        if (t + 1 < nt) {   // stage V[t+1] into the single V buffer
            #pragma unroll
            for (int i = 0; i < 2; ++i) {
                const int r = i * 32 + sr;
                const int cs = sc ^ ((r & 7) << 3);
                gload_lds16(vbase + (size_t)r * 2048 + jn + cs, (char*)Vs + i * 4096 + w * 1024);
            }
        }
    }

    // epilogue: lane holds qrow, d = dt*16 + g*4 + reg
    {
        const float inv_h = 1.0f / l_hi;
        const float inv_l = 1.0f / l_lo;
        unsigned short* orow_h = att + (size_t)(b * N_ + qrow_hi) * 1024 + h * 64;
        unsigned short* orow_l = att + (size_t)(b * N_ + qrow_lo) * 1024 + h * 64;
        #pragma unroll
        for (int dt = 0; dt < 4; ++dt) {
            #pragma unroll
            for (int rp = 0; rp < 2; ++rp) {
                unsigned u = cvt_pk_bf16(oacc_hi[dt][2 * rp] * inv_h,
                                         oacc_hi[dt][2 * rp + 1] * inv_h);
                *reinterpret_cast<unsigned*>(orow_h + dt * 16 + g * 4 + rp * 2) = u;
                u = cvt_pk_bf16(oacc_lo[dt][2 * rp] * inv_l,
                                oacc_lo[dt][2 * rp + 1] * inv_l);
                *reinterpret_cast<unsigned*>(orow_l + dt * 16 + g * 4 + rp * 2) = u;
            }
        }
    }
}

extern "C" void kernel_launch(void* const* d_in, const int* in_sizes, int n_in,
                              void* d_out, int out_size, void* d_ws, size_t ws_size,
                              hipStream_t stream) {
    const float* x     = (const float*)d_in[0];
    const float* pos   = (const float*)d_in[1];
    const float* gamma = (const float*)d_in[2];
    const float* Wq    = (const float*)d_in[3];
    const float* Wkv   = (const float*)d_in[4];
    const float* Wo    = (const float*)d_in[5];
    const float* bo    = (const float*)d_in[6];
    float* out = (float*)d_out;
    char* ws = (char*)d_ws;

    const size_t MB = 1024 * 1024;
    unsigned short* kb   = (unsigned short*)(ws);             // 8 MB roped K [row][1024]
    unsigned short* vb   = (unsigned short*)(ws + 8 * MB);    // 8 MB V [row][1024]
    unsigned short* qb   = (unsigned short*)(ws + 16 * MB);   // 8 MB roped+scaled Q
    unsigned short* xn_b = (unsigned short*)(ws + 24 * MB);   // 8 MB (reused as att)
    unsigned short* xb   = (unsigned short*)(ws + 32 * MB);   // 8 MB
    unsigned short* Wqt  = (unsigned short*)(ws + 40 * MB);   // 2 MB
    unsigned short* Wkvt = (unsigned short*)(ws + 42 * MB);   // 4 MB
    unsigned short* Wot  = (unsigned short*)(ws + 46 * MB);   // 2 MB
    unsigned short* vt   = (unsigned short*)(ws + 48 * MB);   // 8 MB V^T [bh][d][n]
    float2* tabq         = (float2*)(ws + 56 * MB);           // 1 MB
    float2* tabk         = (float2*)(ws + 57 * MB);           // 1 MB
    unsigned short* att  = xn_b;

    freqtab_kernel<<<512, 256, 0, stream>>>(pos, tabq, tabk);
    convT_all_kernel<<<dim3(128, 32), 256, 0, stream>>>(Wq, Wkv, Wo, Wqt, Wkvt, Wot);
    rmsnorm_kernel<<<B_ * N_, 256, 0, stream>>>(x, gamma, xn_b, xb);

    gemm_bf16<128, 2><<<dim3(8, 32), 256, 0, stream>>>(
        xn_b, Wqt, nullptr, qb, nullptr, tabq, 1024);
    gemm_bf16<128, 3><<<dim3(16, 32), 256, 0, stream>>>(
        xb, Wkvt, nullptr, kb, vb, tabk, 1024);

    transposeV_kernel<<<dim3(32, 32), 256, 0, stream>>>(vb, vt);

    attn_mfma_kernel<<<dim3(N_ / 128, B_ * H_), 256, 0, stream>>>(qb, kb, vt, att);

    gemm_bf16<128, 0><<<dim3(8, 32), 256, 0, stream>>>(
        att, Wot, bo, out, nullptr, nullptr, 1024);
}

// Round 9
// 152.749 us; speedup vs baseline: 1.0677x; 1.0677x over previous
//
#include <hip/hip_runtime.h>
#include <cmath>

#define B_ 2
#define N_ 2048
#define D_ 1024
#define H_ 16

typedef __attribute__((ext_vector_type(8))) short short8;
typedef __attribute__((ext_vector_type(4))) float f32x4;
typedef __attribute__((ext_vector_type(4))) unsigned short u16x4;

__device__ __forceinline__ unsigned short f2bf(float f) {
    union { float f; unsigned u; } x;
    x.f = f;
    unsigned r = x.u + 0x7FFFu + ((x.u >> 16) & 1u);
    return (unsigned short)(r >> 16);
}
__device__ __forceinline__ unsigned cvt_pk_bf16(float lo, float hi) {
    unsigned r;
    asm("v_cvt_pk_bf16_f32 %0, %1, %2" : "=v"(r) : "v"(lo), "v"(hi));
    return r;
}
__device__ __forceinline__ float exp2_fast(float x) {
    float r;
    asm("v_exp_f32 %0, %1" : "=v"(r) : "v"(x));
    return r;
}
__device__ __forceinline__ void gload_lds16(const void* g, void* l) {
    __builtin_amdgcn_global_load_lds((const __attribute__((address_space(1))) unsigned*)g,
                                     (__attribute__((address_space(3))) unsigned*)l,
                                     16, 0, 0);
}

// ---------------- cos/sin tables (trig once; q table pre-scaled by 0.125*log2e) ----------------
__global__ __launch_bounds__(256) void freqtab_kernel(const float* __restrict__ pos,
                                                      float2* __restrict__ tabq,
                                                      float2* __restrict__ tabk) {
    const int idx = blockIdx.x * 256 + threadIdx.x;   // N_*64 = 131072
    const float f = pos[idx];
    const float cc = cosf(f), ss = sinf(f);
    const float sq = 0.125f * 1.4426950408889634f;    // DH^-0.5 * log2(e)
    tabq[idx] = make_float2(sq * cc, sq * ss);
    tabk[idx] = make_float2(cc, ss);
}

// ---------------- RMS-like norm -> bf16 xn, plus bf16 copy of x ----------------
__global__ __launch_bounds__(256) void rmsnorm_kernel(const float* __restrict__ x,
                                                      const float* __restrict__ gamma,
                                                      unsigned short* __restrict__ xn,
                                                      unsigned short* __restrict__ xb) {
    const int row = blockIdx.x;
    const float4 v = reinterpret_cast<const float4*>(x + (size_t)row * D_)[threadIdx.x];
    float ss = v.x * v.x + v.y * v.y + v.z * v.z + v.w * v.w;
    #pragma unroll
    for (int off = 32; off; off >>= 1) ss += __shfl_xor(ss, off, 64);
    __shared__ float wss[4];
    if ((threadIdx.x & 63) == 0) wss[threadIdx.x >> 6] = ss;
    __syncthreads();
    const float tot = wss[0] + wss[1] + wss[2] + wss[3];
    const float inv = 1.0f / fmaxf(sqrtf(tot * (1.0f / D_)), 1e-8f);
    const float4 g = reinterpret_cast<const float4*>(gamma)[threadIdx.x];
    u16x4 on, ox;
    on[0] = f2bf(v.x * inv * g.x); on[1] = f2bf(v.y * inv * g.y);
    on[2] = f2bf(v.z * inv * g.z); on[3] = f2bf(v.w * inv * g.w);
    ox[0] = f2bf(v.x); ox[1] = f2bf(v.y); ox[2] = f2bf(v.z); ox[3] = f2bf(v.w);
    *reinterpret_cast<u16x4*>(xn + (size_t)row * D_ + threadIdx.x * 4) = on;
    *reinterpret_cast<u16x4*>(xb + (size_t)row * D_ + threadIdx.x * 4) = ox;
}

// ---------------- all 3 weight transposes in one kernel ----------------
__global__ __launch_bounds__(256) void convT_all_kernel(const float* __restrict__ Wq,
                                                        const float* __restrict__ Wkv,
                                                        const float* __restrict__ Wo,
                                                        unsigned short* __restrict__ Wqt,
                                                        unsigned short* __restrict__ Wkvt,
                                                        unsigned short* __restrict__ Wot) {
    __shared__ float tile[32][33];
    const int bx = blockIdx.x;   // 0..127 over concat {Wq:32, Wkv:64, Wo:32}
    const float* W;
    unsigned short* Wt;
    int Nm, n0;
    if (bx < 32)       { W = Wq;  Wt = Wqt;  Nm = 1024; n0 = bx * 32; }
    else if (bx < 96)  { W = Wkv; Wt = Wkvt; Nm = 2048; n0 = (bx - 32) * 32; }
    else               { W = Wo;  Wt = Wot;  Nm = 1024; n0 = (bx - 96) * 32; }
    const int k0 = blockIdx.y * 32;
    const int r = threadIdx.x >> 3, c4 = (threadIdx.x & 7) * 4;
    const float4 ld = *reinterpret_cast<const float4*>(W + (size_t)(k0 + r) * Nm + n0 + c4);
    tile[r][c4 + 0] = ld.x; tile[r][c4 + 1] = ld.y;
    tile[r][c4 + 2] = ld.z; tile[r][c4 + 3] = ld.w;
    __syncthreads();
    u16x4 o;
    #pragma unroll
    for (int j = 0; j < 4; ++j) o[j] = f2bf(tile[c4 + j][r]);
    *reinterpret_cast<u16x4*>(Wt + (size_t)(n0 + r) * 1024 + k0 + c4) = o;
}

// ---------------- V half (vb) -> Vt[bh][d][n] (bf16) ----------------
__global__ __launch_bounds__(256) void transposeV_kernel(const unsigned short* __restrict__ vb,
                                                         unsigned short* __restrict__ vt) {
    __shared__ unsigned short tile[64][72];
    const int bh = blockIdx.y;
    const int b = bh >> 4, h = bh & 15;
    const int n0 = blockIdx.x * 64;
    const int tid = threadIdx.x;
    const int r = tid >> 3, c = (tid & 7) * 8;
    #pragma unroll
    for (int i = 0; i < 2; ++i) {
        const int n = i * 32 + r;
        const short8 v = *reinterpret_cast<const short8*>(
            vb + (size_t)(b * N_ + n0 + n) * 1024 + h * 64 + c);
        *reinterpret_cast<short8*>(&tile[n][c]) = v;
    }
    __syncthreads();
    #pragma unroll
    for (int i = 0; i < 2; ++i) {
        const int d = i * 32 + r;
        short8 o;
        #pragma unroll
        for (int j = 0; j < 8; ++j) o[j] = (short)tile[c + j][d];
        *reinterpret_cast<short8*>(vt + ((size_t)bh * 64 + d) * 2048 + n0 + c) = o;
    }
}

// ---------------- merged q + kv GEMM (BN=128), rope fused ----------------
// grid (24, 32): x 0-7 -> q (A=xn, rope tabq -> qb); x 8-15 -> K half (A=xb, rope tabk -> kb);
// x 16-23 -> V half (A=xb, plain -> vb). All dst stride 1024.
__global__ __launch_bounds__(256) void gemm_qkv_kernel(const unsigned short* __restrict__ xn,
                                                       const unsigned short* __restrict__ xb,
                                                       const unsigned short* __restrict__ Wqt,
                                                       const unsigned short* __restrict__ Wkvt,
                                                       unsigned short* __restrict__ qb,
                                                       unsigned short* __restrict__ kb,
                                                       unsigned short* __restrict__ vb,
                                                       const float2* __restrict__ tabq,
                                                       const float2* __restrict__ tabk) {
    __shared__ unsigned short As[128 * 64];
    __shared__ unsigned short Bs[128 * 64];
    const int bx = blockIdx.x;
    const unsigned short* A;
    const unsigned short* Bt;
    int n0;
    if (bx < 8)       { A = xn; Bt = Wqt;  n0 = bx * 128; }
    else if (bx < 16) { A = xb; Bt = Wkvt; n0 = (bx - 8) * 128; }
    else              { A = xb; Bt = Wkvt; n0 = (bx - 16) * 128 + 1024; }

    const int tid = threadIdx.x, lane = tid & 63, w = tid >> 6;
    const int m0 = blockIdx.y * 128;
    const int wm = w >> 1, wn = w & 1;
    const int cc = lane & 15;
    const int sr = tid >> 3;
    const int sc = (tid & 7) * 8;

    f32x4 acc[4][4] = {};

    for (int k0 = 0; k0 < 1024; k0 += 64) {
        __syncthreads();
        #pragma unroll
        for (int i = 0; i < 4; ++i) {
            const int r = i * 32 + sr;
            gload_lds16(A + (size_t)(m0 + r) * 1024 + k0 + (sc ^ ((r & 7) << 3)),
                        (char*)As + i * 4096 + w * 1024);
        }
        #pragma unroll
        for (int i = 0; i < 4; ++i) {
            const int r = i * 32 + sr;
            gload_lds16(Bt + (size_t)(n0 + r) * 1024 + k0 + (sc ^ ((r & 7) << 3)),
                        (char*)Bs + i * 4096 + w * 1024);
        }
        __syncthreads();

        short8 af[4][2], bf[4][2];
        #pragma unroll
        for (int mf = 0; mf < 4; ++mf)
            #pragma unroll
            for (int ks = 0; ks < 2; ++ks) {
                const int r = wm * 64 + mf * 16 + cc;
                const int cb = (ks * 64 + ((lane >> 4) * 16)) ^ ((r & 7) << 4);
                af[mf][ks] = *reinterpret_cast<const short8*>((const char*)As + r * 128 + cb);
            }
        #pragma unroll
        for (int nf = 0; nf < 4; ++nf)
            #pragma unroll
            for (int ks = 0; ks < 2; ++ks) {
                const int r = wn * 64 + nf * 16 + cc;
                const int cb = (ks * 64 + ((lane >> 4) * 16)) ^ ((r & 7) << 4);
                bf[nf][ks] = *reinterpret_cast<const short8*>((const char*)Bs + r * 128 + cb);
            }
        #pragma unroll
        for (int ks = 0; ks < 2; ++ks)
            #pragma unroll
            for (int mf = 0; mf < 4; ++mf)
                #pragma unroll
                for (int nf = 0; nf < 4; ++nf)
                    acc[mf][nf] = __builtin_amdgcn_mfma_f32_16x16x32_bf16(af[mf][ks], bf[nf][ks], acc[mf][nf], 0, 0, 0);
    }

    if (bx < 16) {
        // rope epilogue: head = 64-col span (n0 + wn*64); pairs (d, d+32) = (nf, nf+2)
        const float2* tab = (bx < 8) ? tabq : tabk;
        unsigned short* dst = (bx < 8) ? qb : kb;
        #pragma unroll
        for (int mf = 0; mf < 4; ++mf)
            #pragma unroll
            for (int reg = 0; reg < 4; ++reg) {
                const int row = m0 + wm * 64 + mf * 16 + (lane >> 4) * 4 + reg;
                const int n = row & (N_ - 1);
                #pragma unroll
                for (int nf = 0; nf < 2; ++nf) {
                    const int d = nf * 16 + cc;
                    const float2 t1 = tab[n * 64 + d];
                    const float2 t2 = tab[n * 64 + 32 + d];
                    const float x1 = acc[mf][nf][reg];
                    const float x2 = acc[mf][nf + 2][reg];
                    const float o1 = x1 * t1.x - x2 * t1.y;
                    const float o2 = x2 * t2.x + x1 * t2.y;
                    const int col = n0 + wn * 64 + nf * 16 + cc;
                    dst[(size_t)row * 1024 + col] = f2bf(o1);
                    dst[(size_t)row * 1024 + col + 32] = f2bf(o2);
                }
            }
    } else {
        #pragma unroll
        for (int mf = 0; mf < 4; ++mf)
            #pragma unroll
            for (int nf = 0; nf < 4; ++nf)
                #pragma unroll
                for (int reg = 0; reg < 4; ++reg) {
                    const int row = m0 + wm * 64 + mf * 16 + (lane >> 4) * 4 + reg;
                    const int col = n0 - 1024 + wn * 64 + nf * 16 + cc;
                    vb[(size_t)row * 1024 + col] = f2bf(acc[mf][nf][reg]);
                }
    }
}

// ---------------- output GEMM: C = att @ Wot^T + bo (f32 out), BN=64 ----------------
__global__ __launch_bounds__(256) void gemm_o_kernel(const unsigned short* __restrict__ A,
                                                     const unsigned short* __restrict__ Bt,
                                                     const float* __restrict__ bias,
                                                     float* __restrict__ Cout) {
    __shared__ unsigned short As[128 * 64];
    __shared__ unsigned short Bs[64 * 64];
    const int tid = threadIdx.x, lane = tid & 63, w = tid >> 6;
    const int m0 = blockIdx.y * 128, n0 = blockIdx.x * 64;
    const int wm = w >> 1, wn = w & 1;
    const int cc = lane & 15;
    const int sr = tid >> 3;
    const int sc = (tid & 7) * 8;

    f32x4 acc[4][2] = {};

    for (int k0 = 0; k0 < 1024; k0 += 64) {
        __syncthreads();
        #pragma unroll
        for (int i = 0; i < 4; ++i) {
            const int r = i * 32 + sr;
            gload_lds16(A + (size_t)(m0 + r) * 1024 + k0 + (sc ^ ((r & 7) << 3)),
                        (char*)As + i * 4096 + w * 1024);
        }
        #pragma unroll
        for (int i = 0; i < 2; ++i) {
            const int r = i * 32 + sr;
            gload_lds16(Bt + (size_t)(n0 + r) * 1024 + k0 + (sc ^ ((r & 7) << 3)),
                        (char*)Bs + i * 4096 + w * 1024);
        }
        __syncthreads();

        short8 af[4][2], bf[2][2];
        #pragma unroll
        for (int mf = 0; mf < 4; ++mf)
            #pragma unroll
            for (int ks = 0; ks < 2; ++ks) {
                const int r = wm * 64 + mf * 16 + cc;
                const int cb = (ks * 64 + ((lane >> 4) * 16)) ^ ((r & 7) << 4);
                af[mf][ks] = *reinterpret_cast<const short8*>((const char*)As + r * 128 + cb);
            }
        #pragma unroll
        for (int nf = 0; nf < 2; ++nf)
            #pragma unroll
            for (int ks = 0; ks < 2; ++ks) {
                const int r = wn * 32 + nf * 16 + cc;
                const int cb = (ks * 64 + ((lane >> 4) * 16)) ^ ((r & 7) << 4);
                bf[nf][ks] = *reinterpret_cast<const short8*>((const char*)Bs + r * 128 + cb);
            }
        #pragma unroll
        for (int ks = 0; ks < 2; ++ks)
            #pragma unroll
            for (int mf = 0; mf < 4; ++mf)
                #pragma unroll
                for (int nf = 0; nf < 2; ++nf)
                    acc[mf][nf] = __builtin_amdgcn_mfma_f32_16x16x32_bf16(af[mf][ks], bf[nf][ks], acc[mf][nf], 0, 0, 0);
    }

    float bb[2];
    #pragma unroll
    for (int nf = 0; nf < 2; ++nf) bb[nf] = bias[n0 + wn * 32 + nf * 16 + cc];
    #pragma unroll
    for (int mf = 0; mf < 4; ++mf)
        #pragma unroll
        for (int nf = 0; nf < 2; ++nf)
            #pragma unroll
            for (int reg = 0; reg < 4; ++reg) {
                const int row = m0 + wm * 64 + mf * 16 + (lane >> 4) * 4 + reg;
                const int col = n0 + wn * 32 + nf * 16 + cc;
                Cout[(size_t)row * 1024 + col] = acc[mf][nf][reg] + bb[nf];
            }
}

// ---------------- bf16 MFMA causal flash attention ----------------
// 1D grid 1024, XCD-affinity: xcd=bid&7 owns bh = xcd*4 + (slot>>5) (4 bh/XCD -> 2MB K+V, L2-fits).
// 4 waves, wave w owns 16 q rows. K and V both double-buffered, issued together at iteration
// start, vmcnt(4) -> one full iteration to hide load latency. exp2 softmax + defer-max.
__global__ __launch_bounds__(256, 4) void attn_mfma_kernel(const unsigned short* __restrict__ q,
                                                           const unsigned short* __restrict__ kb,
                                                           const unsigned short* __restrict__ vt,
                                                           unsigned short* __restrict__ att) {
    const int bid = blockIdx.x;
    const int xcd = bid & 7;
    const int slot = bid >> 3;          // 0..127
    const int bh = xcd * 4 + (slot >> 5);
    const int qi = slot & 31;
    const int b = bh >> 4, h = bh & 15;
    const int qb = qi * 64;
    const int tid = threadIdx.x;
    const int lane = tid & 63;
    const int w = tid >> 6;
    const int c = lane & 15;
    const int g = lane >> 4;

    __shared__ __align__(16) unsigned short Ks[2][64 * 64];   // [key][d] swizzled
    __shared__ __align__(16) unsigned short Vs[2][64 * 64];   // [d][key] swizzled
    __shared__ __align__(16) unsigned short Ps[4][1024];      // per-wave P^T staging
    char* const PB = (char*)&Ps[w][0];

    const int qrow = qb + w * 16 + c;
    short8 qf[2];
    {
        const unsigned short* qp = q + (size_t)(b * N_ + qrow) * 1024 + h * 64 + g * 8;
        qf[0] = *reinterpret_cast<const short8*>(qp);
        qf[1] = *reinterpret_cast<const short8*>(qp + 32);
    }

    float m = -1e30f, l = 0.f;
    f32x4 oacc[4] = {};

    const int nt = qi + 1;
    const int sr = tid >> 3, sc = (tid & 7) * 8;
    const unsigned short* kbase = kb + (size_t)b * N_ * 1024 + h * 64;
    const unsigned short* vbase = vt + (size_t)bh * 64 * 2048;

    // prologue: stage K0 + V0 into buf 0
    #pragma unroll
    for (int i = 0; i < 2; ++i) {
        const int r = i * 32 + sr;
        const int cs = sc ^ ((r & 7) << 3);
        gload_lds16(kbase + (size_t)r * 1024 + cs, (char*)Ks[0] + i * 4096 + w * 1024);
        gload_lds16(vbase + (size_t)r * 2048 + cs, (char*)Vs[0] + i * 4096 + w * 1024);
    }

    for (int t = 0; t < nt; ++t) {
        const int jb = t * 64;
        if (t + 1 < nt) {
            const int jn = jb + 64;
            char* kd = (char*)Ks[(t + 1) & 1];
            char* vd = (char*)Vs[(t + 1) & 1];
            #pragma unroll
            for (int i = 0; i < 2; ++i) {
                const int r = i * 32 + sr;
                const int cs = sc ^ ((r & 7) << 3);
                gload_lds16(kbase + (size_t)(jn + r) * 1024 + cs, kd + i * 4096 + w * 1024);
                gload_lds16(vbase + (size_t)r * 2048 + jn + cs, vd + i * 4096 + w * 1024);
            }
            asm volatile("s_waitcnt vmcnt(4)" ::: "memory");  // K[t],V[t] landed; 4 next in flight
        } else {
            asm volatile("s_waitcnt vmcnt(0)" ::: "memory");
        }
        __builtin_amdgcn_s_barrier();

        const char* Ksc = (const char*)Ks[t & 1];
        const char* Vsc = (const char*)Vs[t & 1];

        // S^T = K·Q^T : lane holds row=qrow, key = jb + ct*16 + g*4 + reg
        f32x4 st[4];
        __builtin_amdgcn_s_setprio(1);
        #pragma unroll
        for (int ct = 0; ct < 4; ++ct) {
            const int key = ct * 16 + c;
            f32x4 acc = {0.f, 0.f, 0.f, 0.f};
            #pragma unroll
            for (int ks = 0; ks < 2; ++ks) {
                const int addr = (key * 128 + ks * 64 + g * 16) ^ ((key & 7) << 4);
                const short8 kf = *reinterpret_cast<const short8*>(Ksc + addr);
                acc = __builtin_amdgcn_mfma_f32_16x16x32_bf16(kf, qf[ks], acc, 0, 0, 0);
            }
            st[ct] = acc;
        }
        __builtin_amdgcn_s_setprio(0);

        // exp2-domain online softmax with defer-max
        float mx = -1e30f;
        if (jb + 63 > qrow) {   // diagonal tile: mask keys > qrow
            #pragma unroll
            for (int ct = 0; ct < 4; ++ct)
                #pragma unroll
                for (int reg = 0; reg < 4; ++reg) {
                    const int key = jb + ct * 16 + g * 4 + reg;
                    const float sv = (key <= qrow) ? st[ct][reg] : -1e30f;
                    st[ct][reg] = sv;
                    mx = fmaxf(mx, sv);
                }
        } else {
            #pragma unroll
            for (int ct = 0; ct < 4; ++ct)
                mx = fmaxf(mx, fmaxf(fmaxf(st[ct][0], st[ct][1]),
                                     fmaxf(st[ct][2], st[ct][3])));
        }
        mx = fmaxf(mx, __shfl_xor(mx, 16, 64));
        mx = fmaxf(mx, __shfl_xor(mx, 32, 64));
        if (!__all(mx <= m + 8.0f)) {
            const float mn = fmaxf(m, mx);
            const float corr = exp2_fast(m - mn);
            l *= corr;
            m = mn;
            #pragma unroll
            for (int dt = 0; dt < 4; ++dt) {
                oacc[dt][0] *= corr; oacc[dt][1] *= corr;
                oacc[dt][2] *= corr; oacc[dt][3] *= corr;
            }
        }
        float rs = 0.f;
        #pragma unroll
        for (int ct = 0; ct < 4; ++ct)
            #pragma unroll
            for (int reg = 0; reg < 4; ++reg) {
                const float p = exp2_fast(st[ct][reg] - m);
                st[ct][reg] = p;
                rs += p;
            }
        rs += __shfl_xor(rs, 16, 64);
        rs += __shfl_xor(rs, 32, 64);
        l += rs;

        // P^T -> per-wave LDS
        #pragma unroll
        for (int ct = 0; ct < 4; ++ct) {
            uint2 u;
            u.x = cvt_pk_bf16(st[ct][0], st[ct][1]);
            u.y = cvt_pk_bf16(st[ct][2], st[ct][3]);
            const int addr = (c * 128 + ct * 32 + g * 8) ^ ((c & 7) << 4);
            *reinterpret_cast<uint2*>(PB + addr) = u;
        }
        short8 pf[2];
        #pragma unroll
        for (int ks = 0; ks < 2; ++ks) {
            const int addr = (c * 128 + ks * 64 + g * 16) ^ ((c & 7) << 4);
            pf[ks] = *reinterpret_cast<const short8*>(PB + addr);
        }
        // O^T += V^T · P^T
        __builtin_amdgcn_s_setprio(1);
        #pragma unroll
        for (int dt = 0; dt < 4; ++dt) {
            #pragma unroll
            for (int ks = 0; ks < 2; ++ks) {
                const int vd = dt * 16 + c;
                const int addr = (vd * 128 + ks * 64 + g * 16) ^ ((vd & 7) << 4);
                const short8 vf = *reinterpret_cast<const short8*>(Vsc + addr);
                oacc[dt] = __builtin_amdgcn_mfma_f32_16x16x32_bf16(vf, pf[ks], oacc[dt], 0, 0, 0);
            }
        }
        __builtin_amdgcn_s_setprio(0);

        __builtin_amdgcn_s_barrier();   // all waves done with buf[t&1] before it's overwritten
    }

    // epilogue: lane holds qrow, d = dt*16 + g*4 + reg
    {
        const float inv = 1.0f / l;
        unsigned short* orow = att + (size_t)(b * N_ + qrow) * 1024 + h * 64;
        #pragma unroll
        for (int dt = 0; dt < 4; ++dt) {
            #pragma unroll
            for (int rp = 0; rp < 2; ++rp) {
                const unsigned u = cvt_pk_bf16(oacc[dt][2 * rp] * inv,
                                               oacc[dt][2 * rp + 1] * inv);
                *reinterpret_cast<unsigned*>(orow + dt * 16 + g * 4 + rp * 2) = u;
            }
        }
    }
}

extern "C" void kernel_launch(void* const* d_in, const int* in_sizes, int n_in,
                              void* d_out, int out_size, void* d_ws, size_t ws_size,
                              hipStream_t stream) {
    const float* x     = (const float*)d_in[0];
    const float* pos   = (const float*)d_in[1];
    const float* gamma = (const float*)d_in[2];
    const float* Wq    = (const float*)d_in[3];
    const float* Wkv   = (const float*)d_in[4];
    const float* Wo    = (const float*)d_in[5];
    const float* bo    = (const float*)d_in[6];
    float* out = (float*)d_out;
    char* ws = (char*)d_ws;

    const size_t MB = 1024 * 1024;
    unsigned short* kb   = (unsigned short*)(ws);             // 8 MB roped K [row][1024]
    unsigned short* vb   = (unsigned short*)(ws + 8 * MB);    // 8 MB V [row][1024]
    unsigned short* qb   = (unsigned short*)(ws + 16 * MB);   // 8 MB roped+scaled Q
    unsigned short* xn_b = (unsigned short*)(ws + 24 * MB);   // 8 MB (reused as att)
    unsigned short* xb   = (unsigned short*)(ws + 32 * MB);   // 8 MB
    unsigned short* Wqt  = (unsigned short*)(ws + 40 * MB);   // 2 MB
    unsigned short* Wkvt = (unsigned short*)(ws + 42 * MB);   // 4 MB
    unsigned short* Wot  = (unsigned short*)(ws + 46 * MB);   // 2 MB
    unsigned short* vt   = (unsigned short*)(ws + 48 * MB);   // 8 MB V^T [bh][d][n]
    float2* tabq         = (float2*)(ws + 56 * MB);           // 1 MB
    float2* tabk         = (float2*)(ws + 57 * MB);           // 1 MB
    unsigned short* att  = xn_b;

    freqtab_kernel<<<512, 256, 0, stream>>>(pos, tabq, tabk);
    convT_all_kernel<<<dim3(128, 32), 256, 0, stream>>>(Wq, Wkv, Wo, Wqt, Wkvt, Wot);
    rmsnorm_kernel<<<B_ * N_, 256, 0, stream>>>(x, gamma, xn_b, xb);

    gemm_qkv_kernel<<<dim3(24, 32), 256, 0, stream>>>(
        xn_b, xb, Wqt, Wkvt, qb, kb, vb, tabq, tabk);

    transposeV_kernel<<<dim3(32, 32), 256, 0, stream>>>(vb, vt);

    attn_mfma_kernel<<<1024, 256, 0, stream>>>(qb, kb, vt, att);

    gemm_o_kernel<<<dim3(16, 32), 256, 0, stream>>>(att, Wot, bo, out);
}

// Round 10
// 138.330 us; speedup vs baseline: 1.1790x; 1.1042x over previous
//
#include <hip/hip_runtime.h>
#include <cmath>

#define B_ 2
#define N_ 2048
#define D_ 1024
#define H_ 16

typedef __attribute__((ext_vector_type(8))) short short8;
typedef __attribute__((ext_vector_type(4))) float f32x4;
typedef __attribute__((ext_vector_type(4))) unsigned short u16x4;

__device__ __forceinline__ unsigned short f2bf(float f) {
    union { float f; unsigned u; } x;
    x.f = f;
    unsigned r = x.u + 0x7FFFu + ((x.u >> 16) & 1u);
    return (unsigned short)(r >> 16);
}
__device__ __forceinline__ unsigned cvt_pk_bf16(float lo, float hi) {
    unsigned r;
    asm("v_cvt_pk_bf16_f32 %0, %1, %2" : "=v"(r) : "v"(lo), "v"(hi));
    return r;
}
__device__ __forceinline__ float exp2_fast(float x) {
    float r;
    asm("v_exp_f32 %0, %1" : "=v"(r) : "v"(x));
    return r;
}
__device__ __forceinline__ void gload_lds16(const void* g, void* l) {
    __builtin_amdgcn_global_load_lds((const __attribute__((address_space(1))) unsigned*)g,
                                     (__attribute__((address_space(3))) unsigned*)l,
                                     16, 0, 0);
}

// ---------------- cos/sin tables (trig once; q table pre-scaled by 0.125*log2e) ----------------
__global__ __launch_bounds__(256) void freqtab_kernel(const float* __restrict__ pos,
                                                      float2* __restrict__ tabq,
                                                      float2* __restrict__ tabk) {
    const int idx = blockIdx.x * 256 + threadIdx.x;   // N_*64 = 131072
    const float f = pos[idx];
    const float cc = cosf(f), ss = sinf(f);
    const float sq = 0.125f * 1.4426950408889634f;    // DH^-0.5 * log2(e)
    tabq[idx] = make_float2(sq * cc, sq * ss);
    tabk[idx] = make_float2(cc, ss);
}

// ---------------- RMS-like norm -> bf16 xn, plus bf16 copy of x ----------------
__global__ __launch_bounds__(256) void rmsnorm_kernel(const float* __restrict__ x,
                                                      const float* __restrict__ gamma,
                                                      unsigned short* __restrict__ xn,
                                                      unsigned short* __restrict__ xb) {
    const int row = blockIdx.x;
    const float4 v = reinterpret_cast<const float4*>(x + (size_t)row * D_)[threadIdx.x];
    float ss = v.x * v.x + v.y * v.y + v.z * v.z + v.w * v.w;
    #pragma unroll
    for (int off = 32; off; off >>= 1) ss += __shfl_xor(ss, off, 64);
    __shared__ float wss[4];
    if ((threadIdx.x & 63) == 0) wss[threadIdx.x >> 6] = ss;
    __syncthreads();
    const float tot = wss[0] + wss[1] + wss[2] + wss[3];
    const float inv = 1.0f / fmaxf(sqrtf(tot * (1.0f / D_)), 1e-8f);
    const float4 g = reinterpret_cast<const float4*>(gamma)[threadIdx.x];
    u16x4 on, ox;
    on[0] = f2bf(v.x * inv * g.x); on[1] = f2bf(v.y * inv * g.y);
    on[2] = f2bf(v.z * inv * g.z); on[3] = f2bf(v.w * inv * g.w);
    ox[0] = f2bf(v.x); ox[1] = f2bf(v.y); ox[2] = f2bf(v.z); ox[3] = f2bf(v.w);
    *reinterpret_cast<u16x4*>(xn + (size_t)row * D_ + threadIdx.x * 4) = on;
    *reinterpret_cast<u16x4*>(xb + (size_t)row * D_ + threadIdx.x * 4) = ox;
}

// ---------------- all 3 weight transposes in one kernel ----------------
__global__ __launch_bounds__(256) void convT_all_kernel(const float* __restrict__ Wq,
                                                        const float* __restrict__ Wkv,
                                                        const float* __restrict__ Wo,
                                                        unsigned short* __restrict__ Wqt,
                                                        unsigned short* __restrict__ Wkvt,
                                                        unsigned short* __restrict__ Wot) {
    __shared__ float tile[32][33];
    const int bx = blockIdx.x;   // 0..127 over concat {Wq:32, Wkv:64, Wo:32}
    const float* W;
    unsigned short* Wt;
    int Nm, n0;
    if (bx < 32)       { W = Wq;  Wt = Wqt;  Nm = 1024; n0 = bx * 32; }
    else if (bx < 96)  { W = Wkv; Wt = Wkvt; Nm = 2048; n0 = (bx - 32) * 32; }
    else               { W = Wo;  Wt = Wot;  Nm = 1024; n0 = (bx - 96) * 32; }
    const int k0 = blockIdx.y * 32;
    const int r = threadIdx.x >> 3, c4 = (threadIdx.x & 7) * 4;
    const float4 ld = *reinterpret_cast<const float4*>(W + (size_t)(k0 + r) * Nm + n0 + c4);
    tile[r][c4 + 0] = ld.x; tile[r][c4 + 1] = ld.y;
    tile[r][c4 + 2] = ld.z; tile[r][c4 + 3] = ld.w;
    __syncthreads();
    u16x4 o;
    #pragma unroll
    for (int j = 0; j < 4; ++j) o[j] = f2bf(tile[c4 + j][r]);
    *reinterpret_cast<u16x4*>(Wt + (size_t)(n0 + r) * 1024 + k0 + c4) = o;
}

// ---------------- V half (vb) -> Vt[bh][d][n] (bf16) ----------------
__global__ __launch_bounds__(256) void transposeV_kernel(const unsigned short* __restrict__ vb,
                                                         unsigned short* __restrict__ vt) {
    __shared__ unsigned short tile[64][72];
    const int bh = blockIdx.y;
    const int b = bh >> 4, h = bh & 15;
    const int n0 = blockIdx.x * 64;
    const int tid = threadIdx.x;
    const int r = tid >> 3, c = (tid & 7) * 8;
    #pragma unroll
    for (int i = 0; i < 2; ++i) {
        const int n = i * 32 + r;
        const short8 v = *reinterpret_cast<const short8*>(
            vb + (size_t)(b * N_ + n0 + n) * 1024 + h * 64 + c);
        *reinterpret_cast<short8*>(&tile[n][c]) = v;
    }
    __syncthreads();
    #pragma unroll
    for (int i = 0; i < 2; ++i) {
        const int d = i * 32 + r;
        short8 o;
        #pragma unroll
        for (int j = 0; j < 8; ++j) o[j] = (short)tile[c + j][d];
        *reinterpret_cast<short8*>(vt + ((size_t)bh * 64 + d) * 2048 + n0 + c) = o;
    }
}

// ---------------- merged q + kv GEMM (BN=128), rope fused ----------------
// grid (24, 32): x 0-7 -> q (A=xn, rope tabq -> qb); x 8-15 -> K half (A=xb, rope tabk -> kb);
// x 16-23 -> V half (A=xb, plain -> vb). All dst stride 1024.
__global__ __launch_bounds__(256) void gemm_qkv_kernel(const unsigned short* __restrict__ xn,
                                                       const unsigned short* __restrict__ xb,
                                                       const unsigned short* __restrict__ Wqt,
                                                       const unsigned short* __restrict__ Wkvt,
                                                       unsigned short* __restrict__ qb,
                                                       unsigned short* __restrict__ kb,
                                                       unsigned short* __restrict__ vb,
                                                       const float2* __restrict__ tabq,
                                                       const float2* __restrict__ tabk) {
    __shared__ unsigned short As[128 * 64];
    __shared__ unsigned short Bs[128 * 64];
    const int bx = blockIdx.x;
    const unsigned short* A;
    const unsigned short* Bt;
    int n0;
    if (bx < 8)       { A = xn; Bt = Wqt;  n0 = bx * 128; }
    else if (bx < 16) { A = xb; Bt = Wkvt; n0 = (bx - 8) * 128; }
    else              { A = xb; Bt = Wkvt; n0 = (bx - 16) * 128 + 1024; }

    const int tid = threadIdx.x, lane = tid & 63, w = tid >> 6;
    const int m0 = blockIdx.y * 128;
    const int wm = w >> 1, wn = w & 1;
    const int cc = lane & 15;
    const int sr = tid >> 3;
    const int sc = (tid & 7) * 8;

    f32x4 acc[4][4] = {};

    for (int k0 = 0; k0 < 1024; k0 += 64) {
        __syncthreads();
        #pragma unroll
        for (int i = 0; i < 4; ++i) {
            const int r = i * 32 + sr;
            gload_lds16(A + (size_t)(m0 + r) * 1024 + k0 + (sc ^ ((r & 7) << 3)),
                        (char*)As + i * 4096 + w * 1024);
        }
        #pragma unroll
        for (int i = 0; i < 4; ++i) {
            const int r = i * 32 + sr;
            gload_lds16(Bt + (size_t)(n0 + r) * 1024 + k0 + (sc ^ ((r & 7) << 3)),
                        (char*)Bs + i * 4096 + w * 1024);
        }
        __syncthreads();

        short8 af[4][2], bf[4][2];
        #pragma unroll
        for (int mf = 0; mf < 4; ++mf)
            #pragma unroll
            for (int ks = 0; ks < 2; ++ks) {
                const int r = wm * 64 + mf * 16 + cc;
                const int cb = (ks * 64 + ((lane >> 4) * 16)) ^ ((r & 7) << 4);
                af[mf][ks] = *reinterpret_cast<const short8*>((const char*)As + r * 128 + cb);
            }
        #pragma unroll
        for (int nf = 0; nf < 4; ++nf)
            #pragma unroll
            for (int ks = 0; ks < 2; ++ks) {
                const int r = wn * 64 + nf * 16 + cc;
                const int cb = (ks * 64 + ((lane >> 4) * 16)) ^ ((r & 7) << 4);
                bf[nf][ks] = *reinterpret_cast<const short8*>((const char*)Bs + r * 128 + cb);
            }
        #pragma unroll
        for (int ks = 0; ks < 2; ++ks)
            #pragma unroll
            for (int mf = 0; mf < 4; ++mf)
                #pragma unroll
                for (int nf = 0; nf < 4; ++nf)
                    acc[mf][nf] = __builtin_amdgcn_mfma_f32_16x16x32_bf16(af[mf][ks], bf[nf][ks], acc[mf][nf], 0, 0, 0);
    }

    if (bx < 16) {
        // rope epilogue: head = 64-col span (n0 + wn*64); pairs (d, d+32) = (nf, nf+2)
        const float2* tab = (bx < 8) ? tabq : tabk;
        unsigned short* dst = (bx < 8) ? qb : kb;
        #pragma unroll
        for (int mf = 0; mf < 4; ++mf)
            #pragma unroll
            for (int reg = 0; reg < 4; ++reg) {
                const int row = m0 + wm * 64 + mf * 16 + (lane >> 4) * 4 + reg;
                const int n = row & (N_ - 1);
                #pragma unroll
                for (int nf = 0; nf < 2; ++nf) {
                    const int d = nf * 16 + cc;
                    const float2 t1 = tab[n * 64 + d];
                    const float2 t2 = tab[n * 64 + 32 + d];
                    const float x1 = acc[mf][nf][reg];
                    const float x2 = acc[mf][nf + 2][reg];
                    const float o1 = x1 * t1.x - x2 * t1.y;
                    const float o2 = x2 * t2.x + x1 * t2.y;
                    const int col = n0 + wn * 64 + nf * 16 + cc;
                    dst[(size_t)row * 1024 + col] = f2bf(o1);
                    dst[(size_t)row * 1024 + col + 32] = f2bf(o2);
                }
            }
    } else {
        #pragma unroll
        for (int mf = 0; mf < 4; ++mf)
            #pragma unroll
            for (int nf = 0; nf < 4; ++nf)
                #pragma unroll
                for (int reg = 0; reg < 4; ++reg) {
                    const int row = m0 + wm * 64 + mf * 16 + (lane >> 4) * 4 + reg;
                    const int col = n0 - 1024 + wn * 64 + nf * 16 + cc;
                    vb[(size_t)row * 1024 + col] = f2bf(acc[mf][nf][reg]);
                }
    }
}

// ---------------- output GEMM: C = att @ Wot^T + bo (f32 out), BN=64 ----------------
__global__ __launch_bounds__(256) void gemm_o_kernel(const unsigned short* __restrict__ A,
                                                     const unsigned short* __restrict__ Bt,
                                                     const float* __restrict__ bias,
                                                     float* __restrict__ Cout) {
    __shared__ unsigned short As[128 * 64];
    __shared__ unsigned short Bs[64 * 64];
    const int tid = threadIdx.x, lane = tid & 63, w = tid >> 6;
    const int m0 = blockIdx.y * 128, n0 = blockIdx.x * 64;
    const int wm = w >> 1, wn = w & 1;
    const int cc = lane & 15;
    const int sr = tid >> 3;
    const int sc = (tid & 7) * 8;

    f32x4 acc[4][2] = {};

    for (int k0 = 0; k0 < 1024; k0 += 64) {
        __syncthreads();
        #pragma unroll
        for (int i = 0; i < 4; ++i) {
            const int r = i * 32 + sr;
            gload_lds16(A + (size_t)(m0 + r) * 1024 + k0 + (sc ^ ((r & 7) << 3)),
                        (char*)As + i * 4096 + w * 1024);
        }
        #pragma unroll
        for (int i = 0; i < 2; ++i) {
            const int r = i * 32 + sr;
            gload_lds16(Bt + (size_t)(n0 + r) * 1024 + k0 + (sc ^ ((r & 7) << 3)),
                        (char*)Bs + i * 4096 + w * 1024);
        }
        __syncthreads();

        short8 af[4][2], bf[2][2];
        #pragma unroll
        for (int mf = 0; mf < 4; ++mf)
            #pragma unroll
            for (int ks = 0; ks < 2; ++ks) {
                const int r = wm * 64 + mf * 16 + cc;
                const int cb = (ks * 64 + ((lane >> 4) * 16)) ^ ((r & 7) << 4);
                af[mf][ks] = *reinterpret_cast<const short8*>((const char*)As + r * 128 + cb);
            }
        #pragma unroll
        for (int nf = 0; nf < 2; ++nf)
            #pragma unroll
            for (int ks = 0; ks < 2; ++ks) {
                const int r = wn * 32 + nf * 16 + cc;
                const int cb = (ks * 64 + ((lane >> 4) * 16)) ^ ((r & 7) << 4);
                bf[nf][ks] = *reinterpret_cast<const short8*>((const char*)Bs + r * 128 + cb);
            }
        #pragma unroll
        for (int ks = 0; ks < 2; ++ks)
            #pragma unroll
            for (int mf = 0; mf < 4; ++mf)
                #pragma unroll
                for (int nf = 0; nf < 2; ++nf)
                    acc[mf][nf] = __builtin_amdgcn_mfma_f32_16x16x32_bf16(af[mf][ks], bf[nf][ks], acc[mf][nf], 0, 0, 0);
    }

    float bb[2];
    #pragma unroll
    for (int nf = 0; nf < 2; ++nf) bb[nf] = bias[n0 + wn * 32 + nf * 16 + cc];
    #pragma unroll
    for (int mf = 0; mf < 4; ++mf)
        #pragma unroll
        for (int nf = 0; nf < 2; ++nf)
            #pragma unroll
            for (int reg = 0; reg < 4; ++reg) {
                const int row = m0 + wm * 64 + mf * 16 + (lane >> 4) * 4 + reg;
                const int col = n0 + wn * 32 + nf * 16 + cc;
                Cout[(size_t)row * 1024 + col] = acc[mf][nf][reg] + bb[nf];
            }
}

// ---------------- bf16 MFMA causal flash attention ----------------
// 1D grid 1024. xcd = bid&7 (XCD affinity: 4 bh/XCD -> 2MB K+V, L2-fits).
// grp = slot>>5 picks bh within XCD; idx = slot&31; qi = grp odd ? 31-idx : idx
// -> the 4 blocks round-robined onto one CU (slots idx, idx+32, idx+64, idx+96) carry
//    qi = {idx, 31-idx, idx, 31-idx}: per-CU work = 66 tile-units, uniform (no CU tail).
// 4 waves, wave w owns 16 q rows. K,V double-buffered, vmcnt(4). exp2 softmax + defer-max.
__global__ __launch_bounds__(256, 4) void attn_mfma_kernel(const unsigned short* __restrict__ q,
                                                           const unsigned short* __restrict__ kb,
                                                           const unsigned short* __restrict__ vt,
                                                           unsigned short* __restrict__ att) {
    const int bid = blockIdx.x;
    const int xcd = bid & 7;
    const int slot = bid >> 3;          // 0..127
    const int grp = slot >> 5;          // 0..3
    const int idx = slot & 31;
    const int bh = xcd * 4 + grp;
    const int qi = (grp & 1) ? (31 - idx) : idx;
    const int b = bh >> 4, h = bh & 15;
    const int qb = qi * 64;
    const int tid = threadIdx.x;
    const int lane = tid & 63;
    const int w = tid >> 6;
    const int c = lane & 15;
    const int g = lane >> 4;

    __shared__ __align__(16) unsigned short Ks[2][64 * 64];   // [key][d] swizzled
    __shared__ __align__(16) unsigned short Vs[2][64 * 64];   // [d][key] swizzled
    __shared__ __align__(16) unsigned short Ps[4][1024];      // per-wave P^T staging
    char* const PB = (char*)&Ps[w][0];

    const int qrow = qb + w * 16 + c;
    short8 qf[2];
    {
        const unsigned short* qp = q + (size_t)(b * N_ + qrow) * 1024 + h * 64 + g * 8;
        qf[0] = *reinterpret_cast<const short8*>(qp);
        qf[1] = *reinterpret_cast<const short8*>(qp + 32);
    }

    float m = -1e30f, l = 0.f;
    f32x4 oacc[4] = {};

    const int nt = qi + 1;
    const int sr = tid >> 3, sc = (tid & 7) * 8;
    const unsigned short* kbase = kb + (size_t)b * N_ * 1024 + h * 64;
    const unsigned short* vbase = vt + (size_t)bh * 64 * 2048;

    // prologue: stage K0 + V0 into buf 0
    #pragma unroll
    for (int i = 0; i < 2; ++i) {
        const int r = i * 32 + sr;
        const int cs = sc ^ ((r & 7) << 3);
        gload_lds16(kbase + (size_t)r * 1024 + cs, (char*)Ks[0] + i * 4096 + w * 1024);
        gload_lds16(vbase + (size_t)r * 2048 + cs, (char*)Vs[0] + i * 4096 + w * 1024);
    }

    for (int t = 0; t < nt; ++t) {
        const int jb = t * 64;
        if (t + 1 < nt) {
            const int jn = jb + 64;
            char* kd = (char*)Ks[(t + 1) & 1];
            char* vd = (char*)Vs[(t + 1) & 1];
            #pragma unroll
            for (int i = 0; i < 2; ++i) {
                const int r = i * 32 + sr;
                const int cs = sc ^ ((r & 7) << 3);
                gload_lds16(kbase + (size_t)(jn + r) * 1024 + cs, kd + i * 4096 + w * 1024);
                gload_lds16(vbase + (size_t)r * 2048 + jn + cs, vd + i * 4096 + w * 1024);
            }
            asm volatile("s_waitcnt vmcnt(4)" ::: "memory");  // K[t],V[t] landed; 4 next in flight
        } else {
            asm volatile("s_waitcnt vmcnt(0)" ::: "memory");
        }
        __builtin_amdgcn_s_barrier();

        const char* Ksc = (const char*)Ks[t & 1];
        const char* Vsc = (const char*)Vs[t & 1];

        // S^T = K·Q^T : lane holds row=qrow, key = jb + ct*16 + g*4 + reg
        f32x4 st[4];
        __builtin_amdgcn_s_setprio(1);
        #pragma unroll
        for (int ct = 0; ct < 4; ++ct) {
            const int key = ct * 16 + c;
            f32x4 acc = {0.f, 0.f, 0.f, 0.f};
            #pragma unroll
            for (int ks = 0; ks < 2; ++ks) {
                const int addr = (key * 128 + ks * 64 + g * 16) ^ ((key & 7) << 4);
                const short8 kf = *reinterpret_cast<const short8*>(Ksc + addr);
                acc = __builtin_amdgcn_mfma_f32_16x16x32_bf16(kf, qf[ks], acc, 0, 0, 0);
            }
            st[ct] = acc;
        }
        __builtin_amdgcn_s_setprio(0);

        // exp2-domain online softmax with defer-max
        float mx = -1e30f;
        if (jb + 63 > qrow) {   // diagonal tile: mask keys > qrow
            #pragma unroll
            for (int ct = 0; ct < 4; ++ct)
                #pragma unroll
                for (int reg = 0; reg < 4; ++reg) {
                    const int key = jb + ct * 16 + g * 4 + reg;
                    const float sv = (key <= qrow) ? st[ct][reg] : -1e30f;
                    st[ct][reg] = sv;
                    mx = fmaxf(mx, sv);
                }
        } else {
            #pragma unroll
            for (int ct = 0; ct < 4; ++ct)
                mx = fmaxf(mx, fmaxf(fmaxf(st[ct][0], st[ct][1]),
                                     fmaxf(st[ct][2], st[ct][3])));
        }
        mx = fmaxf(mx, __shfl_xor(mx, 16, 64));
        mx = fmaxf(mx, __shfl_xor(mx, 32, 64));
        if (!__all(mx <= m + 8.0f)) {
            const float mn = fmaxf(m, mx);
            const float corr = exp2_fast(m - mn);
            l *= corr;
            m = mn;
            #pragma unroll
            for (int dt = 0; dt < 4; ++dt) {
                oacc[dt][0] *= corr; oacc[dt][1] *= corr;
                oacc[dt][2] *= corr; oacc[dt][3] *= corr;
            }
        }
        float rs = 0.f;
        #pragma unroll
        for (int ct = 0; ct < 4; ++ct)
            #pragma unroll
            for (int reg = 0; reg < 4; ++reg) {
                const float p = exp2_fast(st[ct][reg] - m);
                st[ct][reg] = p;
                rs += p;
            }
        rs += __shfl_xor(rs, 16, 64);
        rs += __shfl_xor(rs, 32, 64);
        l += rs;

        // P^T -> per-wave LDS
        #pragma unroll
        for (int ct = 0; ct < 4; ++ct) {
            uint2 u;
            u.x = cvt_pk_bf16(st[ct][0], st[ct][1]);
            u.y = cvt_pk_bf16(st[ct][2], st[ct][3]);
            const int addr = (c * 128 + ct * 32 + g * 8) ^ ((c & 7) << 4);
            *reinterpret_cast<uint2*>(PB + addr) = u;
        }
        short8 pf[2];
        #pragma unroll
        for (int ks = 0; ks < 2; ++ks) {
            const int addr = (c * 128 + ks * 64 + g * 16) ^ ((c & 7) << 4);
            pf[ks] = *reinterpret_cast<const short8*>(PB + addr);
        }
        // O^T += V^T · P^T
        __builtin_amdgcn_s_setprio(1);
        #pragma unroll
        for (int dt = 0; dt < 4; ++dt) {
            #pragma unroll
            for (int ks = 0; ks < 2; ++ks) {
                const int vd = dt * 16 + c;
                const int addr = (vd * 128 + ks * 64 + g * 16) ^ ((vd & 7) << 4);
                const short8 vf = *reinterpret_cast<const short8*>(Vsc + addr);
                oacc[dt] = __builtin_amdgcn_mfma_f32_16x16x32_bf16(vf, pf[ks], oacc[dt], 0, 0, 0);
            }
        }
        __builtin_amdgcn_s_setprio(0);

        __builtin_amdgcn_s_barrier();   // all waves done with buf[t&1] before it's overwritten
    }

    // epilogue: lane holds qrow, d = dt*16 + g*4 + reg
    {
        const float inv = 1.0f / l;
        unsigned short* orow = att + (size_t)(b * N_ + qrow) * 1024 + h * 64;
        #pragma unroll
        for (int dt = 0; dt < 4; ++dt) {
            #pragma unroll
            for (int rp = 0; rp < 2; ++rp) {
                const unsigned u = cvt_pk_bf16(oacc[dt][2 * rp] * inv,
                                               oacc[dt][2 * rp + 1] * inv);
                *reinterpret_cast<unsigned*>(orow + dt * 16 + g * 4 + rp * 2) = u;
            }
        }
    }
}

extern "C" void kernel_launch(void* const* d_in, const int* in_sizes, int n_in,
                              void* d_out, int out_size, void* d_ws, size_t ws_size,
                              hipStream_t stream) {
    const float* x     = (const float*)d_in[0];
    const float* pos   = (const float*)d_in[1];
    const float* gamma = (const float*)d_in[2];
    const float* Wq    = (const float*)d_in[3];
    const float* Wkv   = (const float*)d_in[4];
    const float* Wo    = (const float*)d_in[5];
    const float* bo    = (const float*)d_in[6];
    float* out = (float*)d_out;
    char* ws = (char*)d_ws;

    const size_t MB = 1024 * 1024;
    unsigned short* kb   = (unsigned short*)(ws);             // 8 MB roped K [row][1024]
    unsigned short* vb   = (unsigned short*)(ws + 8 * MB);    // 8 MB V [row][1024]
    unsigned short* qb   = (unsigned short*)(ws + 16 * MB);   // 8 MB roped+scaled Q
    unsigned short* xn_b = (unsigned short*)(ws + 24 * MB);   // 8 MB (reused as att)
    unsigned short* xb   = (unsigned short*)(ws + 32 * MB);   // 8 MB
    unsigned short* Wqt  = (unsigned short*)(ws + 40 * MB);   // 2 MB
    unsigned short* Wkvt = (unsigned short*)(ws + 42 * MB);   // 4 MB
    unsigned short* Wot  = (unsigned short*)(ws + 46 * MB);   // 2 MB
    unsigned short* vt   = (unsigned short*)(ws + 48 * MB);   // 8 MB V^T [bh][d][n]
    float2* tabq         = (float2*)(ws + 56 * MB);           // 1 MB
    float2* tabk         = (float2*)(ws + 57 * MB);           // 1 MB
    unsigned short* att  = xn_b;

    freqtab_kernel<<<512, 256, 0, stream>>>(pos, tabq, tabk);
    convT_all_kernel<<<dim3(128, 32), 256, 0, stream>>>(Wq, Wkv, Wo, Wqt, Wkvt, Wot);
    rmsnorm_kernel<<<B_ * N_, 256, 0, stream>>>(x, gamma, xn_b, xb);

    gemm_qkv_kernel<<<dim3(24, 32), 256, 0, stream>>>(
        xn_b, xb, Wqt, Wkvt, qb, kb, vb, tabq, tabk);

    transposeV_kernel<<<dim3(32, 32), 256, 0, stream>>>(vb, vt);

    attn_mfma_kernel<<<1024, 256, 0, stream>>>(qb, kb, vt, att);

    gemm_o_kernel<<<dim3(16, 32), 256, 0, stream>>>(att, Wot, bo, out);
}

// Round 11
// 134.327 us; speedup vs baseline: 1.2141x; 1.0298x over previous
//
#include <hip/hip_runtime.h>
#include <cmath>

#define B_ 2
#define N_ 2048
#define D_ 1024
#define H_ 16

typedef __attribute__((ext_vector_type(8))) short short8;
typedef __attribute__((ext_vector_type(4))) float f32x4;
typedef __attribute__((ext_vector_type(4))) unsigned short u16x4;

__device__ __forceinline__ unsigned short f2bf(float f) {
    union { float f; unsigned u; } x;
    x.f = f;
    unsigned r = x.u + 0x7FFFu + ((x.u >> 16) & 1u);
    return (unsigned short)(r >> 16);
}
__device__ __forceinline__ unsigned cvt_pk_bf16(float lo, float hi) {
    unsigned r;
    asm("v_cvt_pk_bf16_f32 %0, %1, %2" : "=v"(r) : "v"(lo), "v"(hi));
    return r;
}
__device__ __forceinline__ float exp2_fast(float x) {
    float r;
    asm("v_exp_f32 %0, %1" : "=v"(r) : "v"(x));
    return r;
}
__device__ __forceinline__ void gload_lds16(const void* g, void* l) {
    __builtin_amdgcn_global_load_lds((const __attribute__((address_space(1))) unsigned*)g,
                                     (__attribute__((address_space(3))) unsigned*)l,
                                     16, 0, 0);
}

// ---------------- cos/sin tables (trig once; q table pre-scaled by 0.125*log2e) ----------------
__global__ __launch_bounds__(256) void freqtab_kernel(const float* __restrict__ pos,
                                                      float2* __restrict__ tabq,
                                                      float2* __restrict__ tabk) {
    const int idx = blockIdx.x * 256 + threadIdx.x;   // N_*64 = 131072
    const float f = pos[idx];
    const float cc = cosf(f), ss = sinf(f);
    const float sq = 0.125f * 1.4426950408889634f;    // DH^-0.5 * log2(e)
    tabq[idx] = make_float2(sq * cc, sq * ss);
    tabk[idx] = make_float2(cc, ss);
}

// ---------------- RMS-like norm: emit bf16 x copy + per-row scale s ----------------
__global__ __launch_bounds__(256) void rmsnorm_kernel(const float* __restrict__ x,
                                                      unsigned short* __restrict__ xb,
                                                      float* __restrict__ s) {
    const int row = blockIdx.x;
    const float4 v = reinterpret_cast<const float4*>(x + (size_t)row * D_)[threadIdx.x];
    float ss = v.x * v.x + v.y * v.y + v.z * v.z + v.w * v.w;
    #pragma unroll
    for (int off = 32; off; off >>= 1) ss += __shfl_xor(ss, off, 64);
    __shared__ float wss[4];
    if ((threadIdx.x & 63) == 0) wss[threadIdx.x >> 6] = ss;
    __syncthreads();
    const float tot = wss[0] + wss[1] + wss[2] + wss[3];
    const float inv = 1.0f / fmaxf(sqrtf(tot * (1.0f / D_)), 1e-8f);
    if (threadIdx.x == 0) s[row] = inv;
    u16x4 ox;
    ox[0] = f2bf(v.x); ox[1] = f2bf(v.y); ox[2] = f2bf(v.z); ox[3] = f2bf(v.w);
    *reinterpret_cast<u16x4*>(xb + (size_t)row * D_ + threadIdx.x * 4) = ox;
}

// ---------------- all 3 weight transposes (gamma folded into Wq) ----------------
__global__ __launch_bounds__(256) void convT_all_kernel(const float* __restrict__ Wq,
                                                        const float* __restrict__ Wkv,
                                                        const float* __restrict__ Wo,
                                                        const float* __restrict__ gamma,
                                                        unsigned short* __restrict__ Wqt,
                                                        unsigned short* __restrict__ Wkvt,
                                                        unsigned short* __restrict__ Wot) {
    __shared__ float tile[32][33];
    const int bx = blockIdx.x;   // 0..127 over concat {Wq:32, Wkv:64, Wo:32}
    const float* W;
    unsigned short* Wt;
    int Nm, n0;
    bool gmul = false;
    if (bx < 32)       { W = Wq;  Wt = Wqt;  Nm = 1024; n0 = bx * 32; gmul = true; }
    else if (bx < 96)  { W = Wkv; Wt = Wkvt; Nm = 2048; n0 = (bx - 32) * 32; }
    else               { W = Wo;  Wt = Wot;  Nm = 1024; n0 = (bx - 96) * 32; }
    const int k0 = blockIdx.y * 32;
    const int r = threadIdx.x >> 3, c4 = (threadIdx.x & 7) * 4;
    const float4 ld = *reinterpret_cast<const float4*>(W + (size_t)(k0 + r) * Nm + n0 + c4);
    tile[r][c4 + 0] = ld.x; tile[r][c4 + 1] = ld.y;
    tile[r][c4 + 2] = ld.z; tile[r][c4 + 3] = ld.w;
    __syncthreads();
    u16x4 o;
    #pragma unroll
    for (int j = 0; j < 4; ++j) {
        float v = tile[c4 + j][r];
        if (gmul) v *= gamma[k0 + c4 + j];
        o[j] = f2bf(v);
    }
    *reinterpret_cast<u16x4*>(Wt + (size_t)(n0 + r) * 1024 + k0 + c4) = o;
}

// ---------------- merged q + kv GEMM (BN=128), rope fused, V written transposed ----------------
// 1D grid 768, XCD-affine: xcd=bid&7 owns bx in [3*xcd, 3*xcd+3) (B-panels L2-resident).
// bx 0-7: q = s_row*(xb @ (gamma.Wq)) + rope(tabq) -> qb
// bx 8-15: K = rope(tabk, xb @ Wkv[:, :1024]) -> kb
// bx 16-23: V = xb @ Wkv[:, 1024:] -> vt[bh][d][n] directly (transposed store)
__global__ __launch_bounds__(256) void gemm_qkv_kernel(const unsigned short* __restrict__ xb,
                                                       const unsigned short* __restrict__ Wqt,
                                                       const unsigned short* __restrict__ Wkvt,
                                                       const float* __restrict__ s,
                                                       unsigned short* __restrict__ qb,
                                                       unsigned short* __restrict__ kb,
                                                       unsigned short* __restrict__ vt,
                                                       const float2* __restrict__ tabq,
                                                       const float2* __restrict__ tabk) {
    __shared__ unsigned short As[128 * 64];
    __shared__ unsigned short Bs[128 * 64];
    __shared__ float sld[128];
    const int bid = blockIdx.x;
    const int xcd = bid & 7;
    const int ii = bid >> 3;                 // 0..95
    const int bx = xcd * 3 + (ii % 3);       // 0..23
    const int m0 = (ii / 3) * 128;

    const unsigned short* Bt;
    int n0;
    if (bx < 8)       { Bt = Wqt;  n0 = bx * 128; }
    else if (bx < 16) { Bt = Wkvt; n0 = (bx - 8) * 128; }
    else              { Bt = Wkvt; n0 = (bx - 16) * 128 + 1024; }

    const int tid = threadIdx.x, lane = tid & 63, w = tid >> 6;
    const int wm = w >> 1, wn = w & 1;
    const int cc = lane & 15;
    const int sr = tid >> 3;
    const int sc = (tid & 7) * 8;

    if (tid < 128) sld[tid] = s[m0 + tid];

    f32x4 acc[4][4] = {};

    for (int k0 = 0; k0 < 1024; k0 += 64) {
        __syncthreads();
        #pragma unroll
        for (int i = 0; i < 4; ++i) {
            const int r = i * 32 + sr;
            gload_lds16(xb + (size_t)(m0 + r) * 1024 + k0 + (sc ^ ((r & 7) << 3)),
                        (char*)As + i * 4096 + w * 1024);
        }
        #pragma unroll
        for (int i = 0; i < 4; ++i) {
            const int r = i * 32 + sr;
            gload_lds16(Bt + (size_t)(n0 + r) * 1024 + k0 + (sc ^ ((r & 7) << 3)),
                        (char*)Bs + i * 4096 + w * 1024);
        }
        __syncthreads();

        short8 af[4][2], bf[4][2];
        #pragma unroll
        for (int mf = 0; mf < 4; ++mf)
            #pragma unroll
            for (int ks = 0; ks < 2; ++ks) {
                const int r = wm * 64 + mf * 16 + cc;
                const int cb = (ks * 64 + ((lane >> 4) * 16)) ^ ((r & 7) << 4);
                af[mf][ks] = *reinterpret_cast<const short8*>((const char*)As + r * 128 + cb);
            }
        #pragma unroll
        for (int nf = 0; nf < 4; ++nf)
            #pragma unroll
            for (int ks = 0; ks < 2; ++ks) {
                const int r = wn * 64 + nf * 16 + cc;
                const int cb = (ks * 64 + ((lane >> 4) * 16)) ^ ((r & 7) << 4);
                bf[nf][ks] = *reinterpret_cast<const short8*>((const char*)Bs + r * 128 + cb);
            }
        #pragma unroll
        for (int ks = 0; ks < 2; ++ks)
            #pragma unroll
            for (int mf = 0; mf < 4; ++mf)
                #pragma unroll
                for (int nf = 0; nf < 4; ++nf)
                    acc[mf][nf] = __builtin_amdgcn_mfma_f32_16x16x32_bf16(af[mf][ks], bf[nf][ks], acc[mf][nf], 0, 0, 0);
    }

    if (bx < 16) {
        // rope epilogue; q additionally scaled by per-row s (f32)
        const float2* tab = (bx < 8) ? tabq : tabk;
        unsigned short* dst = (bx < 8) ? qb : kb;
        const bool doscale = (bx < 8);
        #pragma unroll
        for (int mf = 0; mf < 4; ++mf)
            #pragma unroll
            for (int reg = 0; reg < 4; ++reg) {
                const int rloc = wm * 64 + mf * 16 + (lane >> 4) * 4 + reg;
                const int row = m0 + rloc;
                const int n = row & (N_ - 1);
                const float srow = doscale ? sld[rloc] : 1.0f;
                #pragma unroll
                for (int nf = 0; nf < 2; ++nf) {
                    const int d = nf * 16 + cc;
                    const float2 t1 = tab[n * 64 + d];
                    const float2 t2 = tab[n * 64 + 32 + d];
                    const float x1 = acc[mf][nf][reg] * srow;
                    const float x2 = acc[mf][nf + 2][reg] * srow;
                    const float o1 = x1 * t1.x - x2 * t1.y;
                    const float o2 = x2 * t2.x + x1 * t2.y;
                    const int col = n0 + wn * 64 + nf * 16 + cc;
                    dst[(size_t)row * 1024 + col] = f2bf(o1);
                    dst[(size_t)row * 1024 + col + 32] = f2bf(o2);
                }
            }
    } else {
        // V: store transposed into vt[bh*64+d][n] (reg axis = 4 consecutive n -> 8B store)
        const int bb = m0 >> 11;                 // batch
        const int nbase = (m0 & (N_ - 1)) + wm * 64;
        #pragma unroll
        for (int mf = 0; mf < 4; ++mf) {
            const int nloc = nbase + mf * 16 + (lane >> 4) * 4;
            #pragma unroll
            for (int nf = 0; nf < 4; ++nf) {
                const int cv = n0 - 1024 + wn * 64 + nf * 16 + cc;   // 0..1023
                const int h = cv >> 6, d = cv & 63;
                uint2 u;
                u.x = cvt_pk_bf16(acc[mf][nf][0], acc[mf][nf][1]);
                u.y = cvt_pk_bf16(acc[mf][nf][2], acc[mf][nf][3]);
                *reinterpret_cast<uint2*>(vt + ((size_t)(bb * 16 + h) * 64 + d) * 2048 + nloc) = u;
            }
        }
    }
}

// ---------------- output GEMM: C = att @ Wot^T + bo (f32 out), BN=64, XCD-affine ----------------
__global__ __launch_bounds__(256) void gemm_o_kernel(const unsigned short* __restrict__ A,
                                                     const unsigned short* __restrict__ Bt,
                                                     const float* __restrict__ bias,
                                                     float* __restrict__ Cout) {
    __shared__ unsigned short As[128 * 64];
    __shared__ unsigned short Bs[64 * 64];
    const int bid = blockIdx.x;
    const int xcd = bid & 7;
    const int ii = bid >> 3;                 // 0..63
    const int n0 = (xcd * 2 + (ii & 1)) * 64;
    const int m0 = (ii >> 1) * 128;
    const int tid = threadIdx.x, lane = tid & 63, w = tid >> 6;
    const int wm = w >> 1, wn = w & 1;
    const int cc = lane & 15;
    const int sr = tid >> 3;
    const int sc = (tid & 7) * 8;

    f32x4 acc[4][2] = {};

    for (int k0 = 0; k0 < 1024; k0 += 64) {
        __syncthreads();
        #pragma unroll
        for (int i = 0; i < 4; ++i) {
            const int r = i * 32 + sr;
            gload_lds16(A + (size_t)(m0 + r) * 1024 + k0 + (sc ^ ((r & 7) << 3)),
                        (char*)As + i * 4096 + w * 1024);
        }
        #pragma unroll
        for (int i = 0; i < 2; ++i) {
            const int r = i * 32 + sr;
            gload_lds16(Bt + (size_t)(n0 + r) * 1024 + k0 + (sc ^ ((r & 7) << 3)),
                        (char*)Bs + i * 4096 + w * 1024);
        }
        __syncthreads();

        short8 af[4][2], bf[2][2];
        #pragma unroll
        for (int mf = 0; mf < 4; ++mf)
            #pragma unroll
            for (int ks = 0; ks < 2; ++ks) {
                const int r = wm * 64 + mf * 16 + cc;
                const int cb = (ks * 64 + ((lane >> 4) * 16)) ^ ((r & 7) << 4);
                af[mf][ks] = *reinterpret_cast<const short8*>((const char*)As + r * 128 + cb);
            }
        #pragma unroll
        for (int nf = 0; nf < 2; ++nf)
            #pragma unroll
            for (int ks = 0; ks < 2; ++ks) {
                const int r = wn * 32 + nf * 16 + cc;
                const int cb = (ks * 64 + ((lane >> 4) * 16)) ^ ((r & 7) << 4);
                bf[nf][ks] = *reinterpret_cast<const short8*>((const char*)Bs + r * 128 + cb);
            }
        #pragma unroll
        for (int ks = 0; ks < 2; ++ks)
            #pragma unroll
            for (int mf = 0; mf < 4; ++mf)
                #pragma unroll
                for (int nf = 0; nf < 2; ++nf)
                    acc[mf][nf] = __builtin_amdgcn_mfma_f32_16x16x32_bf16(af[mf][ks], bf[nf][ks], acc[mf][nf], 0, 0, 0);
    }

    float bb[2];
    #pragma unroll
    for (int nf = 0; nf < 2; ++nf) bb[nf] = bias[n0 + wn * 32 + nf * 16 + cc];
    #pragma unroll
    for (int mf = 0; mf < 4; ++mf)
        #pragma unroll
        for (int nf = 0; nf < 2; ++nf)
            #pragma unroll
            for (int reg = 0; reg < 4; ++reg) {
                const int row = m0 + wm * 64 + mf * 16 + (lane >> 4) * 4 + reg;
                const int col = n0 + wn * 32 + nf * 16 + cc;
                Cout[(size_t)row * 1024 + col] = acc[mf][nf][reg] + bb[nf];
            }
}

// ---------------- bf16 MFMA causal flash attention (unchanged from R10) ----------------
__global__ __launch_bounds__(256, 4) void attn_mfma_kernel(const unsigned short* __restrict__ q,
                                                           const unsigned short* __restrict__ kb,
                                                           const unsigned short* __restrict__ vt,
                                                           unsigned short* __restrict__ att) {
    const int bid = blockIdx.x;
    const int xcd = bid & 7;
    const int slot = bid >> 3;          // 0..127
    const int grp = slot >> 5;          // 0..3
    const int idx = slot & 31;
    const int bh = xcd * 4 + grp;
    const int qi = (grp & 1) ? (31 - idx) : idx;
    const int b = bh >> 4, h = bh & 15;
    const int qb_ = qi * 64;
    const int tid = threadIdx.x;
    const int lane = tid & 63;
    const int w = tid >> 6;
    const int c = lane & 15;
    const int g = lane >> 4;

    __shared__ __align__(16) unsigned short Ks[2][64 * 64];   // [key][d] swizzled
    __shared__ __align__(16) unsigned short Vs[2][64 * 64];   // [d][key] swizzled
    __shared__ __align__(16) unsigned short Ps[4][1024];      // per-wave P^T staging
    char* const PB = (char*)&Ps[w][0];

    const int qrow = qb_ + w * 16 + c;
    short8 qf[2];
    {
        const unsigned short* qp = q + (size_t)(b * N_ + qrow) * 1024 + h * 64 + g * 8;
        qf[0] = *reinterpret_cast<const short8*>(qp);
        qf[1] = *reinterpret_cast<const short8*>(qp + 32);
    }

    float m = -1e30f, l = 0.f;
    f32x4 oacc[4] = {};

    const int nt = qi + 1;
    const int sr = tid >> 3, sc = (tid & 7) * 8;
    const unsigned short* kbase = kb + (size_t)b * N_ * 1024 + h * 64;
    const unsigned short* vbase = vt + (size_t)bh * 64 * 2048;

    #pragma unroll
    for (int i = 0; i < 2; ++i) {
        const int r = i * 32 + sr;
        const int cs = sc ^ ((r & 7) << 3);
        gload_lds16(kbase + (size_t)r * 1024 + cs, (char*)Ks[0] + i * 4096 + w * 1024);
        gload_lds16(vbase + (size_t)r * 2048 + cs, (char*)Vs[0] + i * 4096 + w * 1024);
    }

    for (int t = 0; t < nt; ++t) {
        const int jb = t * 64;
        if (t + 1 < nt) {
            const int jn = jb + 64;
            char* kd = (char*)Ks[(t + 1) & 1];
            char* vd = (char*)Vs[(t + 1) & 1];
            #pragma unroll
            for (int i = 0; i < 2; ++i) {
                const int r = i * 32 + sr;
                const int cs = sc ^ ((r & 7) << 3);
                gload_lds16(kbase + (size_t)(jn + r) * 1024 + cs, kd + i * 4096 + w * 1024);
                gload_lds16(vbase + (size_t)r * 2048 + jn + cs, vd + i * 4096 + w * 1024);
            }
            asm volatile("s_waitcnt vmcnt(4)" ::: "memory");
        } else {
            asm volatile("s_waitcnt vmcnt(0)" ::: "memory");
        }
        __builtin_amdgcn_s_barrier();

        const char* Ksc = (const char*)Ks[t & 1];
        const char* Vsc = (const char*)Vs[t & 1];

        f32x4 st[4];
        __builtin_amdgcn_s_setprio(1);
        #pragma unroll
        for (int ct = 0; ct < 4; ++ct) {
            const int key = ct * 16 + c;
            f32x4 acc = {0.f, 0.f, 0.f, 0.f};
            #pragma unroll
            for (int ks = 0; ks < 2; ++ks) {
                const int addr = (key * 128 + ks * 64 + g * 16) ^ ((key & 7) << 4);
                const short8 kf = *reinterpret_cast<const short8*>(Ksc + addr);
                acc = __builtin_amdgcn_mfma_f32_16x16x32_bf16(kf, qf[ks], acc, 0, 0, 0);
            }
            st[ct] = acc;
        }
        __builtin_amdgcn_s_setprio(0);

        float mx = -1e30f;
        if (jb + 63 > qrow) {
            #pragma unroll
            for (int ct = 0; ct < 4; ++ct)
                #pragma unroll
                for (int reg = 0; reg < 4; ++reg) {
                    const int key = jb + ct * 16 + g * 4 + reg;
                    const float sv = (key <= qrow) ? st[ct][reg] : -1e30f;
                    st[ct][reg] = sv;
                    mx = fmaxf(mx, sv);
                }
        } else {
            #pragma unroll
            for (int ct = 0; ct < 4; ++ct)
                mx = fmaxf(mx, fmaxf(fmaxf(st[ct][0], st[ct][1]),
                                     fmaxf(st[ct][2], st[ct][3])));
        }
        mx = fmaxf(mx, __shfl_xor(mx, 16, 64));
        mx = fmaxf(mx, __shfl_xor(mx, 32, 64));
        if (!__all(mx <= m + 8.0f)) {
            const float mn = fmaxf(m, mx);
            const float corr = exp2_fast(m - mn);
            l *= corr;
            m = mn;
            #pragma unroll
            for (int dt = 0; dt < 4; ++dt) {
                oacc[dt][0] *= corr; oacc[dt][1] *= corr;
                oacc[dt][2] *= corr; oacc[dt][3] *= corr;
            }
        }
        float rs = 0.f;
        #pragma unroll
        for (int ct = 0; ct < 4; ++ct)
            #pragma unroll
            for (int reg = 0; reg < 4; ++reg) {
                const float p = exp2_fast(st[ct][reg] - m);
                st[ct][reg] = p;
                rs += p;
            }
        rs += __shfl_xor(rs, 16, 64);
        rs += __shfl_xor(rs, 32, 64);
        l += rs;

        #pragma unroll
        for (int ct = 0; ct < 4; ++ct) {
            uint2 u;
            u.x = cvt_pk_bf16(st[ct][0], st[ct][1]);
            u.y = cvt_pk_bf16(st[ct][2], st[ct][3]);
            const int addr = (c * 128 + ct * 32 + g * 8) ^ ((c & 7) << 4);
            *reinterpret_cast<uint2*>(PB + addr) = u;
        }
        short8 pf[2];
        #pragma unroll
        for (int ks = 0; ks < 2; ++ks) {
            const int addr = (c * 128 + ks * 64 + g * 16) ^ ((c & 7) << 4);
            pf[ks] = *reinterpret_cast<const short8*>(PB + addr);
        }
        __builtin_amdgcn_s_setprio(1);
        #pragma unroll
        for (int dt = 0; dt < 4; ++dt) {
            #pragma unroll
            for (int ks = 0; ks < 2; ++ks) {
                const int vd = dt * 16 + c;
                const int addr = (vd * 128 + ks * 64 + g * 16) ^ ((vd & 7) << 4);
                const short8 vf = *reinterpret_cast<const short8*>(Vsc + addr);
                oacc[dt] = __builtin_amdgcn_mfma_f32_16x16x32_bf16(vf, pf[ks], oacc[dt], 0, 0, 0);
            }
        }
        __builtin_amdgcn_s_setprio(0);

        __builtin_amdgcn_s_barrier();
    }

    {
        const float inv = 1.0f / l;
        unsigned short* orow = att + (size_t)(b * N_ + qrow) * 1024 + h * 64;
        #pragma unroll
        for (int dt = 0; dt < 4; ++dt) {
            #pragma unroll
            for (int rp = 0; rp < 2; ++rp) {
                const unsigned u = cvt_pk_bf16(oacc[dt][2 * rp] * inv,
                                               oacc[dt][2 * rp + 1] * inv);
                *reinterpret_cast<unsigned*>(orow + dt * 16 + g * 4 + rp * 2) = u;
            }
        }
    }
}

extern "C" void kernel_launch(void* const* d_in, const int* in_sizes, int n_in,
                              void* d_out, int out_size, void* d_ws, size_t ws_size,
                              hipStream_t stream) {
    const float* x     = (const float*)d_in[0];
    const float* pos   = (const float*)d_in[1];
    const float* gamma = (const float*)d_in[2];
    const float* Wq    = (const float*)d_in[3];
    const float* Wkv   = (const float*)d_in[4];
    const float* Wo    = (const float*)d_in[5];
    const float* bo    = (const float*)d_in[6];
    float* out = (float*)d_out;
    char* ws = (char*)d_ws;

    const size_t MB = 1024 * 1024;
    unsigned short* kb   = (unsigned short*)(ws);             // 8 MB roped K [row][1024]
    unsigned short* qb   = (unsigned short*)(ws + 16 * MB);   // 8 MB roped+scaled Q
    unsigned short* att  = (unsigned short*)(ws + 24 * MB);   // 8 MB attention output
    unsigned short* xb   = (unsigned short*)(ws + 32 * MB);   // 8 MB bf16 x
    unsigned short* Wqt  = (unsigned short*)(ws + 40 * MB);   // 2 MB (gamma-folded)
    unsigned short* Wkvt = (unsigned short*)(ws + 42 * MB);   // 4 MB
    unsigned short* Wot  = (unsigned short*)(ws + 46 * MB);   // 2 MB
    unsigned short* vt   = (unsigned short*)(ws + 48 * MB);   // 8 MB V^T [bh][d][n]
    float2* tabq         = (float2*)(ws + 56 * MB);           // 1 MB
    float2* tabk         = (float2*)(ws + 57 * MB);           // 1 MB
    float* sv            = (float*)(ws + 58 * MB);            // 16 KB per-row scale

    freqtab_kernel<<<512, 256, 0, stream>>>(pos, tabq, tabk);
    convT_all_kernel<<<dim3(128, 32), 256, 0, stream>>>(Wq, Wkv, Wo, gamma, Wqt, Wkvt, Wot);
    rmsnorm_kernel<<<B_ * N_, 256, 0, stream>>>(x, xb, sv);

    gemm_qkv_kernel<<<768, 256, 0, stream>>>(
        xb, Wqt, Wkvt, sv, qb, kb, vt, tabq, tabk);

    attn_mfma_kernel<<<1024, 256, 0, stream>>>(qb, kb, vt, att);

    gemm_o_kernel<<<512, 256, 0, stream>>>(att, Wot, bo, out);
}

// Round 12
// 129.173 us; speedup vs baseline: 1.2626x; 1.0399x over previous
//
#include <hip/hip_runtime.h>
#include <cmath>

#define B_ 2
#define N_ 2048
#define D_ 1024
#define H_ 16

typedef __attribute__((ext_vector_type(8))) short short8;
typedef __attribute__((ext_vector_type(4))) float f32x4;
typedef __attribute__((ext_vector_type(4))) unsigned short u16x4;

__device__ __forceinline__ unsigned short f2bf(float f) {
    union { float f; unsigned u; } x;
    x.f = f;
    unsigned r = x.u + 0x7FFFu + ((x.u >> 16) & 1u);
    return (unsigned short)(r >> 16);
}
__device__ __forceinline__ unsigned cvt_pk_bf16(float lo, float hi) {
    unsigned r;
    asm("v_cvt_pk_bf16_f32 %0, %1, %2" : "=v"(r) : "v"(lo), "v"(hi));
    return r;
}
__device__ __forceinline__ float exp2_fast(float x) {
    float r;
    asm("v_exp_f32 %0, %1" : "=v"(r) : "v"(x));
    return r;
}
__device__ __forceinline__ void gload_lds16(const void* g, void* l) {
    __builtin_amdgcn_global_load_lds((const __attribute__((address_space(1))) unsigned*)g,
                                     (__attribute__((address_space(3))) unsigned*)l,
                                     16, 0, 0);
}

// ---------------- cos/sin tables (trig once; q table pre-scaled by 0.125*log2e) ----------------
__global__ __launch_bounds__(256) void freqtab_kernel(const float* __restrict__ pos,
                                                      float2* __restrict__ tabq,
                                                      float2* __restrict__ tabk) {
    const int idx = blockIdx.x * 256 + threadIdx.x;   // N_*64 = 131072
    const float f = pos[idx];
    const float cc = cosf(f), ss = sinf(f);
    const float sq = 0.125f * 1.4426950408889634f;    // DH^-0.5 * log2(e)
    tabq[idx] = make_float2(sq * cc, sq * ss);
    tabk[idx] = make_float2(cc, ss);
}

// ---------------- RMS-like norm: emit bf16 x copy + per-row scale s ----------------
__global__ __launch_bounds__(256) void rmsnorm_kernel(const float* __restrict__ x,
                                                      unsigned short* __restrict__ xb,
                                                      float* __restrict__ s) {
    const int row = blockIdx.x;
    const float4 v = reinterpret_cast<const float4*>(x + (size_t)row * D_)[threadIdx.x];
    float ss = v.x * v.x + v.y * v.y + v.z * v.z + v.w * v.w;
    #pragma unroll
    for (int off = 32; off; off >>= 1) ss += __shfl_xor(ss, off, 64);
    __shared__ float wss[4];
    if ((threadIdx.x & 63) == 0) wss[threadIdx.x >> 6] = ss;
    __syncthreads();
    const float tot = wss[0] + wss[1] + wss[2] + wss[3];
    const float inv = 1.0f / fmaxf(sqrtf(tot * (1.0f / D_)), 1e-8f);
    if (threadIdx.x == 0) s[row] = inv;
    u16x4 ox;
    ox[0] = f2bf(v.x); ox[1] = f2bf(v.y); ox[2] = f2bf(v.z); ox[3] = f2bf(v.w);
    *reinterpret_cast<u16x4*>(xb + (size_t)row * D_ + threadIdx.x * 4) = ox;
}

// ---------------- all 3 weight transposes (gamma folded into Wq) ----------------
__global__ __launch_bounds__(256) void convT_all_kernel(const float* __restrict__ Wq,
                                                        const float* __restrict__ Wkv,
                                                        const float* __restrict__ Wo,
                                                        const float* __restrict__ gamma,
                                                        unsigned short* __restrict__ Wqt,
                                                        unsigned short* __restrict__ Wkvt,
                                                        unsigned short* __restrict__ Wot) {
    __shared__ float tile[32][33];
    const int bx = blockIdx.x;   // 0..127 over concat {Wq:32, Wkv:64, Wo:32}
    const float* W;
    unsigned short* Wt;
    int Nm, n0;
    bool gmul = false;
    if (bx < 32)       { W = Wq;  Wt = Wqt;  Nm = 1024; n0 = bx * 32; gmul = true; }
    else if (bx < 96)  { W = Wkv; Wt = Wkvt; Nm = 2048; n0 = (bx - 32) * 32; }
    else               { W = Wo;  Wt = Wot;  Nm = 1024; n0 = (bx - 96) * 32; }
    const int k0 = blockIdx.y * 32;
    const int r = threadIdx.x >> 3, c4 = (threadIdx.x & 7) * 4;
    const float4 ld = *reinterpret_cast<const float4*>(W + (size_t)(k0 + r) * Nm + n0 + c4);
    tile[r][c4 + 0] = ld.x; tile[r][c4 + 1] = ld.y;
    tile[r][c4 + 2] = ld.z; tile[r][c4 + 3] = ld.w;
    __syncthreads();
    u16x4 o;
    #pragma unroll
    for (int j = 0; j < 4; ++j) {
        float v = tile[c4 + j][r];
        if (gmul) v *= gamma[k0 + c4 + j];
        o[j] = f2bf(v);
    }
    *reinterpret_cast<u16x4*>(Wt + (size_t)(n0 + r) * 1024 + k0 + c4) = o;
}

// ---------------- merged q + kv GEMM (BN=128), rope fused, V transposed, dbuf pipeline ----------------
// 1D grid 768, XCD-affine: xcd=bid&7 owns bx in [3*xcd, 3*xcd+3).
// Double-buffered LDS + counted vmcnt(8): next K-step's 8 global_load_lds issued before
// this step's compute; latency hides under MFMA (same pattern as attn kernel).
__global__ __launch_bounds__(256) void gemm_qkv_kernel(const unsigned short* __restrict__ xb,
                                                       const unsigned short* __restrict__ Wqt,
                                                       const unsigned short* __restrict__ Wkvt,
                                                       const float* __restrict__ s,
                                                       unsigned short* __restrict__ qb,
                                                       unsigned short* __restrict__ kb,
                                                       unsigned short* __restrict__ vt,
                                                       const float2* __restrict__ tabq,
                                                       const float2* __restrict__ tabk) {
    __shared__ unsigned short As[2][128 * 64];
    __shared__ unsigned short Bs[2][128 * 64];
    __shared__ float sld[128];
    const int bid = blockIdx.x;
    const int xcd = bid & 7;
    const int ii = bid >> 3;                 // 0..95
    const int bx = xcd * 3 + (ii % 3);       // 0..23
    const int m0 = (ii / 3) * 128;

    const unsigned short* Bt;
    int n0;
    if (bx < 8)       { Bt = Wqt;  n0 = bx * 128; }
    else if (bx < 16) { Bt = Wkvt; n0 = (bx - 8) * 128; }
    else              { Bt = Wkvt; n0 = (bx - 16) * 128 + 1024; }

    const int tid = threadIdx.x, lane = tid & 63, w = tid >> 6;
    const int wm = w >> 1, wn = w & 1;
    const int cc = lane & 15;
    const int sr = tid >> 3;
    const int sc = (tid & 7) * 8;

    if (tid < 128) sld[tid] = s[m0 + tid];

    f32x4 acc[4][4] = {};

    // prologue: stage K-step 0 into buf 0
    #pragma unroll
    for (int i = 0; i < 4; ++i) {
        const int r = i * 32 + sr;
        const int cs = sc ^ ((r & 7) << 3);
        gload_lds16(xb + (size_t)(m0 + r) * 1024 + cs, (char*)As[0] + i * 4096 + w * 1024);
        gload_lds16(Bt + (size_t)(n0 + r) * 1024 + cs, (char*)Bs[0] + i * 4096 + w * 1024);
    }

    for (int t = 0; t < 16; ++t) {
        if (t + 1 < 16) {
            const int k0 = (t + 1) * 64;
            char* ad = (char*)As[(t + 1) & 1];
            char* bd = (char*)Bs[(t + 1) & 1];
            #pragma unroll
            for (int i = 0; i < 4; ++i) {
                const int r = i * 32 + sr;
                const int cs = sc ^ ((r & 7) << 3);
                gload_lds16(xb + (size_t)(m0 + r) * 1024 + k0 + cs, ad + i * 4096 + w * 1024);
                gload_lds16(Bt + (size_t)(n0 + r) * 1024 + k0 + cs, bd + i * 4096 + w * 1024);
            }
            asm volatile("s_waitcnt vmcnt(8)" ::: "memory");  // this step landed; next 8 flying
        } else {
            asm volatile("s_waitcnt vmcnt(0)" ::: "memory");
        }
        __builtin_amdgcn_s_barrier();

        const char* Ac = (const char*)As[t & 1];
        const char* Bc = (const char*)Bs[t & 1];

        short8 af[4][2], bf[4][2];
        #pragma unroll
        for (int mf = 0; mf < 4; ++mf)
            #pragma unroll
            for (int ks = 0; ks < 2; ++ks) {
                const int r = wm * 64 + mf * 16 + cc;
                const int cb = (ks * 64 + ((lane >> 4) * 16)) ^ ((r & 7) << 4);
                af[mf][ks] = *reinterpret_cast<const short8*>(Ac + r * 128 + cb);
            }
        #pragma unroll
        for (int nf = 0; nf < 4; ++nf)
            #pragma unroll
            for (int ks = 0; ks < 2; ++ks) {
                const int r = wn * 64 + nf * 16 + cc;
                const int cb = (ks * 64 + ((lane >> 4) * 16)) ^ ((r & 7) << 4);
                bf[nf][ks] = *reinterpret_cast<const short8*>(Bc + r * 128 + cb);
            }
        #pragma unroll
        for (int ks = 0; ks < 2; ++ks)
            #pragma unroll
            for (int mf = 0; mf < 4; ++mf)
                #pragma unroll
                for (int nf = 0; nf < 4; ++nf)
                    acc[mf][nf] = __builtin_amdgcn_mfma_f32_16x16x32_bf16(af[mf][ks], bf[nf][ks], acc[mf][nf], 0, 0, 0);

        __builtin_amdgcn_s_barrier();   // all waves done with buf[t&1] before overwrite
    }

    if (bx < 16) {
        // rope epilogue; q additionally scaled by per-row s (f32)
        const float2* tab = (bx < 8) ? tabq : tabk;
        unsigned short* dst = (bx < 8) ? qb : kb;
        const bool doscale = (bx < 8);
        #pragma unroll
        for (int mf = 0; mf < 4; ++mf)
            #pragma unroll
            for (int reg = 0; reg < 4; ++reg) {
                const int rloc = wm * 64 + mf * 16 + (lane >> 4) * 4 + reg;
                const int row = m0 + rloc;
                const int n = row & (N_ - 1);
                const float srow = doscale ? sld[rloc] : 1.0f;
                #pragma unroll
                for (int nf = 0; nf < 2; ++nf) {
                    const int d = nf * 16 + cc;
                    const float2 t1 = tab[n * 64 + d];
                    const float2 t2 = tab[n * 64 + 32 + d];
                    const float x1 = acc[mf][nf][reg] * srow;
                    const float x2 = acc[mf][nf + 2][reg] * srow;
                    const float o1 = x1 * t1.x - x2 * t1.y;
                    const float o2 = x2 * t2.x + x1 * t2.y;
                    const int col = n0 + wn * 64 + nf * 16 + cc;
                    dst[(size_t)row * 1024 + col] = f2bf(o1);
                    dst[(size_t)row * 1024 + col + 32] = f2bf(o2);
                }
            }
    } else {
        // V: store transposed into vt[bh*64+d][n] (reg axis = 4 consecutive n -> 8B store)
        const int bb = m0 >> 11;                 // batch
        const int nbase = (m0 & (N_ - 1)) + wm * 64;
        #pragma unroll
        for (int mf = 0; mf < 4; ++mf) {
            const int nloc = nbase + mf * 16 + (lane >> 4) * 4;
            #pragma unroll
            for (int nf = 0; nf < 4; ++nf) {
                const int cv = n0 - 1024 + wn * 64 + nf * 16 + cc;   // 0..1023
                const int h = cv >> 6, d = cv & 63;
                uint2 u;
                u.x = cvt_pk_bf16(acc[mf][nf][0], acc[mf][nf][1]);
                u.y = cvt_pk_bf16(acc[mf][nf][2], acc[mf][nf][3]);
                *reinterpret_cast<uint2*>(vt + ((size_t)(bb * 16 + h) * 64 + d) * 2048 + nloc) = u;
            }
        }
    }
}

// ---------------- output GEMM: C = att @ Wot^T + bo (f32 out), BN=64, XCD-affine, dbuf ----------------
__global__ __launch_bounds__(256) void gemm_o_kernel(const unsigned short* __restrict__ A,
                                                     const unsigned short* __restrict__ Bt,
                                                     const float* __restrict__ bias,
                                                     float* __restrict__ Cout) {
    __shared__ unsigned short As[2][128 * 64];
    __shared__ unsigned short Bs[2][64 * 64];
    const int bid = blockIdx.x;
    const int xcd = bid & 7;
    const int ii = bid >> 3;                 // 0..63
    const int n0 = (xcd * 2 + (ii & 1)) * 64;
    const int m0 = (ii >> 1) * 128;
    const int tid = threadIdx.x, lane = tid & 63, w = tid >> 6;
    const int wm = w >> 1, wn = w & 1;
    const int cc = lane & 15;
    const int sr = tid >> 3;
    const int sc = (tid & 7) * 8;

    f32x4 acc[4][2] = {};

    // prologue
    #pragma unroll
    for (int i = 0; i < 4; ++i) {
        const int r = i * 32 + sr;
        const int cs = sc ^ ((r & 7) << 3);
        gload_lds16(A + (size_t)(m0 + r) * 1024 + cs, (char*)As[0] + i * 4096 + w * 1024);
        if (i < 2)
            gload_lds16(Bt + (size_t)(n0 + r) * 1024 + cs, (char*)Bs[0] + i * 4096 + w * 1024);
    }

    for (int t = 0; t < 16; ++t) {
        if (t + 1 < 16) {
            const int k0 = (t + 1) * 64;
            char* ad = (char*)As[(t + 1) & 1];
            char* bd = (char*)Bs[(t + 1) & 1];
            #pragma unroll
            for (int i = 0; i < 4; ++i) {
                const int r = i * 32 + sr;
                const int cs = sc ^ ((r & 7) << 3);
                gload_lds16(A + (size_t)(m0 + r) * 1024 + k0 + cs, ad + i * 4096 + w * 1024);
                if (i < 2)
                    gload_lds16(Bt + (size_t)(n0 + r) * 1024 + k0 + cs, bd + i * 4096 + w * 1024);
            }
            asm volatile("s_waitcnt vmcnt(6)" ::: "memory");
        } else {
            asm volatile("s_waitcnt vmcnt(0)" ::: "memory");
        }
        __builtin_amdgcn_s_barrier();

        const char* Ac = (const char*)As[t & 1];
        const char* Bc = (const char*)Bs[t & 1];

        short8 af[4][2], bf[2][2];
        #pragma unroll
        for (int mf = 0; mf < 4; ++mf)
            #pragma unroll
            for (int ks = 0; ks < 2; ++ks) {
                const int r = wm * 64 + mf * 16 + cc;
                const int cb = (ks * 64 + ((lane >> 4) * 16)) ^ ((r & 7) << 4);
                af[mf][ks] = *reinterpret_cast<const short8*>(Ac + r * 128 + cb);
            }
        #pragma unroll
        for (int nf = 0; nf < 2; ++nf)
            #pragma unroll
            for (int ks = 0; ks < 2; ++ks) {
                const int r = wn * 32 + nf * 16 + cc;
                const int cb = (ks * 64 + ((lane >> 4) * 16)) ^ ((r & 7) << 4);
                bf[nf][ks] = *reinterpret_cast<const short8*>(Bc + r * 128 + cb);
            }
        #pragma unroll
        for (int ks = 0; ks < 2; ++ks)
            #pragma unroll
            for (int mf = 0; mf < 4; ++mf)
                #pragma unroll
                for (int nf = 0; nf < 2; ++nf)
                    acc[mf][nf] = __builtin_amdgcn_mfma_f32_16x16x32_bf16(af[mf][ks], bf[nf][ks], acc[mf][nf], 0, 0, 0);

        __builtin_amdgcn_s_barrier();
    }

    float bb[2];
    #pragma unroll
    for (int nf = 0; nf < 2; ++nf) bb[nf] = bias[n0 + wn * 32 + nf * 16 + cc];
    #pragma unroll
    for (int mf = 0; mf < 4; ++mf)
        #pragma unroll
        for (int nf = 0; nf < 2; ++nf)
            #pragma unroll
            for (int reg = 0; reg < 4; ++reg) {
                const int row = m0 + wm * 64 + mf * 16 + (lane >> 4) * 4 + reg;
                const int col = n0 + wn * 32 + nf * 16 + cc;
                Cout[(size_t)row * 1024 + col] = acc[mf][nf][reg] + bb[nf];
            }
}

// ---------------- bf16 MFMA causal flash attention (unchanged) ----------------
__global__ __launch_bounds__(256, 4) void attn_mfma_kernel(const unsigned short* __restrict__ q,
                                                           const unsigned short* __restrict__ kb,
                                                           const unsigned short* __restrict__ vt,
                                                           unsigned short* __restrict__ att) {
    const int bid = blockIdx.x;
    const int xcd = bid & 7;
    const int slot = bid >> 3;          // 0..127
    const int grp = slot >> 5;          // 0..3
    const int idx = slot & 31;
    const int bh = xcd * 4 + grp;
    const int qi = (grp & 1) ? (31 - idx) : idx;
    const int b = bh >> 4, h = bh & 15;
    const int qb_ = qi * 64;
    const int tid = threadIdx.x;
    const int lane = tid & 63;
    const int w = tid >> 6;
    const int c = lane & 15;
    const int g = lane >> 4;

    __shared__ __align__(16) unsigned short Ks[2][64 * 64];   // [key][d] swizzled
    __shared__ __align__(16) unsigned short Vs[2][64 * 64];   // [d][key] swizzled
    __shared__ __align__(16) unsigned short Ps[4][1024];      // per-wave P^T staging
    char* const PB = (char*)&Ps[w][0];

    const int qrow = qb_ + w * 16 + c;
    short8 qf[2];
    {
        const unsigned short* qp = q + (size_t)(b * N_ + qrow) * 1024 + h * 64 + g * 8;
        qf[0] = *reinterpret_cast<const short8*>(qp);
        qf[1] = *reinterpret_cast<const short8*>(qp + 32);
    }

    float m = -1e30f, l = 0.f;
    f32x4 oacc[4] = {};

    const int nt = qi + 1;
    const int sr = tid >> 3, sc = (tid & 7) * 8;
    const unsigned short* kbase = kb + (size_t)b * N_ * 1024 + h * 64;
    const unsigned short* vbase = vt + (size_t)bh * 64 * 2048;

    #pragma unroll
    for (int i = 0; i < 2; ++i) {
        const int r = i * 32 + sr;
        const int cs = sc ^ ((r & 7) << 3);
        gload_lds16(kbase + (size_t)r * 1024 + cs, (char*)Ks[0] + i * 4096 + w * 1024);
        gload_lds16(vbase + (size_t)r * 2048 + cs, (char*)Vs[0] + i * 4096 + w * 1024);
    }

    for (int t = 0; t < nt; ++t) {
        const int jb = t * 64;
        if (t + 1 < nt) {
            const int jn = jb + 64;
            char* kd = (char*)Ks[(t + 1) & 1];
            char* vd = (char*)Vs[(t + 1) & 1];
            #pragma unroll
            for (int i = 0; i < 2; ++i) {
                const int r = i * 32 + sr;
                const int cs = sc ^ ((r & 7) << 3);
                gload_lds16(kbase + (size_t)(jn + r) * 1024 + cs, kd + i * 4096 + w * 1024);
                gload_lds16(vbase + (size_t)r * 2048 + jn + cs, vd + i * 4096 + w * 1024);
            }
            asm volatile("s_waitcnt vmcnt(4)" ::: "memory");
        } else {
            asm volatile("s_waitcnt vmcnt(0)" ::: "memory");
        }
        __builtin_amdgcn_s_barrier();

        const char* Ksc = (const char*)Ks[t & 1];
        const char* Vsc = (const char*)Vs[t & 1];

        f32x4 st[4];
        __builtin_amdgcn_s_setprio(1);
        #pragma unroll
        for (int ct = 0; ct < 4; ++ct) {
            const int key = ct * 16 + c;
            f32x4 acc = {0.f, 0.f, 0.f, 0.f};
            #pragma unroll
            for (int ks = 0; ks < 2; ++ks) {
                const int addr = (key * 128 + ks * 64 + g * 16) ^ ((key & 7) << 4);
                const short8 kf = *reinterpret_cast<const short8*>(Ksc + addr);
                acc = __builtin_amdgcn_mfma_f32_16x16x32_bf16(kf, qf[ks], acc, 0, 0, 0);
            }
            st[ct] = acc;
        }
        __builtin_amdgcn_s_setprio(0);

        float mx = -1e30f;
        if (jb + 63 > qrow) {
            #pragma unroll
            for (int ct = 0; ct < 4; ++ct)
                #pragma unroll
                for (int reg = 0; reg < 4; ++reg) {
                    const int key = jb + ct * 16 + g * 4 + reg;
                    const float sv = (key <= qrow) ? st[ct][reg] : -1e30f;
                    st[ct][reg] = sv;
                    mx = fmaxf(mx, sv);
                }
        } else {
            #pragma unroll
            for (int ct = 0; ct < 4; ++ct)
                mx = fmaxf(mx, fmaxf(fmaxf(st[ct][0], st[ct][1]),
                                     fmaxf(st[ct][2], st[ct][3])));
        }
        mx = fmaxf(mx, __shfl_xor(mx, 16, 64));
        mx = fmaxf(mx, __shfl_xor(mx, 32, 64));
        if (!__all(mx <= m + 8.0f)) {
            const float mn = fmaxf(m, mx);
            const float corr = exp2_fast(m - mn);
            l *= corr;
            m = mn;
            #pragma unroll
            for (int dt = 0; dt < 4; ++dt) {
                oacc[dt][0] *= corr; oacc[dt][1] *= corr;
                oacc[dt][2] *= corr; oacc[dt][3] *= corr;
            }
        }
        float rs = 0.f;
        #pragma unroll
        for (int ct = 0; ct < 4; ++ct)
            #pragma unroll
            for (int reg = 0; reg < 4; ++reg) {
                const float p = exp2_fast(st[ct][reg] - m);
                st[ct][reg] = p;
                rs += p;
            }
        rs += __shfl_xor(rs, 16, 64);
        rs += __shfl_xor(rs, 32, 64);
        l += rs;

        #pragma unroll
        for (int ct = 0; ct < 4; ++ct) {
            uint2 u;
            u.x = cvt_pk_bf16(st[ct][0], st[ct][1]);
            u.y = cvt_pk_bf16(st[ct][2], st[ct][3]);
            const int addr = (c * 128 + ct * 32 + g * 8) ^ ((c & 7) << 4);
            *reinterpret_cast<uint2*>(PB + addr) = u;
        }
        short8 pf[2];
        #pragma unroll
        for (int ks = 0; ks < 2; ++ks) {
            const int addr = (c * 128 + ks * 64 + g * 16) ^ ((c & 7) << 4);
            pf[ks] = *reinterpret_cast<const short8*>(PB + addr);
        }
        __builtin_amdgcn_s_setprio(1);
        #pragma unroll
        for (int dt = 0; dt < 4; ++dt) {
            #pragma unroll
            for (int ks = 0; ks < 2; ++ks) {
                const int vd = dt * 16 + c;
                const int addr = (vd * 128 + ks * 64 + g * 16) ^ ((vd & 7) << 4);
                const short8 vf = *reinterpret_cast<const short8*>(Vsc + addr);
                oacc[dt] = __builtin_amdgcn_mfma_f32_16x16x32_bf16(vf, pf[ks], oacc[dt], 0, 0, 0);
            }
        }
        __builtin_amdgcn_s_setprio(0);

        __builtin_amdgcn_s_barrier();
    }

    {
        const float inv = 1.0f / l;
        unsigned short* orow = att + (size_t)(b * N_ + qrow) * 1024 + h * 64;
        #pragma unroll
        for (int dt = 0; dt < 4; ++dt) {
            #pragma unroll
            for (int rp = 0; rp < 2; ++rp) {
                const unsigned u = cvt_pk_bf16(oacc[dt][2 * rp] * inv,
                                               oacc[dt][2 * rp + 1] * inv);
                *reinterpret_cast<unsigned*>(orow + dt * 16 + g * 4 + rp * 2) = u;
            }
        }
    }
}

extern "C" void kernel_launch(void* const* d_in, const int* in_sizes, int n_in,
                              void* d_out, int out_size, void* d_ws, size_t ws_size,
                              hipStream_t stream) {
    const float* x     = (const float*)d_in[0];
    const float* pos   = (const float*)d_in[1];
    const float* gamma = (const float*)d_in[2];
    const float* Wq    = (const float*)d_in[3];
    const float* Wkv   = (const float*)d_in[4];
    const float* Wo    = (const float*)d_in[5];
    const float* bo    = (const float*)d_in[6];
    float* out = (float*)d_out;
    char* ws = (char*)d_ws;

    const size_t MB = 1024 * 1024;
    unsigned short* kb   = (unsigned short*)(ws);             // 8 MB roped K [row][1024]
    unsigned short* qb   = (unsigned short*)(ws + 16 * MB);   // 8 MB roped+scaled Q
    unsigned short* att  = (unsigned short*)(ws + 24 * MB);   // 8 MB attention output
    unsigned short* xb   = (unsigned short*)(ws + 32 * MB);   // 8 MB bf16 x
    unsigned short* Wqt  = (unsigned short*)(ws + 40 * MB);   // 2 MB (gamma-folded)
    unsigned short* Wkvt = (unsigned short*)(ws + 42 * MB);   // 4 MB
    unsigned short* Wot  = (unsigned short*)(ws + 46 * MB);   // 2 MB
    unsigned short* vt   = (unsigned short*)(ws + 48 * MB);   // 8 MB V^T [bh][d][n]
    float2* tabq         = (float2*)(ws + 56 * MB);           // 1 MB
    float2* tabk         = (float2*)(ws + 57 * MB);           // 1 MB
    float* sv            = (float*)(ws + 58 * MB);            // 16 KB per-row scale

    freqtab_kernel<<<512, 256, 0, stream>>>(pos, tabq, tabk);
    convT_all_kernel<<<dim3(128, 32), 256, 0, stream>>>(Wq, Wkv, Wo, gamma, Wqt, Wkvt, Wot);
    rmsnorm_kernel<<<B_ * N_, 256, 0, stream>>>(x, xb, sv);

    gemm_qkv_kernel<<<768, 256, 0, stream>>>(
        xb, Wqt, Wkvt, sv, qb, kb, vt, tabq, tabk);

    attn_mfma_kernel<<<1024, 256, 0, stream>>>(qb, kb, vt, att);

    gemm_o_kernel<<<512, 256, 0, stream>>>(att, Wot, bo, out);
}